// Round 11
// baseline (227.931 us; speedup 1.0000x reference)
//
#include <hip/hip_runtime.h>

#define NT    262144
#define SDIM  32
#define NSEG  4096           // speculative segments; one WAVE runs FOUR chains
#define SEG   (NT / NSEG)    // 64 steps per segment
#define WARM  48             // warm-up steps; WARM < SEG => warm windows disjoint
#define NBLK  (NSEG / 4)     // 1024 blocks
#define EPSV  1e-12f
#define L2E   1.4426950408889634f   // log2(e)
#define LN2   0.6931471805599453f
// warm-window copies in d_ws: NSEG windows (window 0 = dummy) of WARM x 32
#define WSW   ((size_t)NSEG * WARM * SDIM)
#define WS_NEEDED (2 * WSW * 4)     // 50.3 MB, proven available rounds 6-10

#define PIN(X_) asm volatile("" : "+v"(X_))

// ---------------------------------------------------------------------------
// Kernel 1: gl/rl precompute (pre-negated-scaled for exp2 sigmoids) + compact
// warm-window copies (unchanged from round 10).
// ---------------------------------------------------------------------------
__global__ void precompute_lin(const float* __restrict__ X,
                               const float* __restrict__ gb,
                               const float* __restrict__ rg,
                               float* __restrict__ glN,
                               float* __restrict__ rlN,
                               float* __restrict__ wsgl,   // may be null
                               float* __restrict__ wsrl)
{
    int idx = blockIdx.x * blockDim.x + threadIdx.x;   // covers (NT/2)*32
    int t0 = idx >> 5, i = idx & 31;
    int t1 = t0 + NT / 2;
    const float4* xr0 = (const float4*)(X + (size_t)t0 * 32);
    const float4* xr1 = (const float4*)(X + (size_t)t1 * 32);
    float a0 = 0.f, c0 = 0.f, a1 = 0.f, c1 = 0.f;
#pragma unroll
    for (int q = 0; q < 8; ++q) {
        float4 x0 = xr0[q], x1 = xr1[q];
#pragma unroll
        for (int u = 0; u < 4; ++u) {
            int j = 4 * q + u;
            float gv = gb[j * 32 + i], rv = rg[j * 32 + i];
            float xe0 = (u == 0) ? x0.x : (u == 1) ? x0.y : (u == 2) ? x0.z : x0.w;
            float xe1 = (u == 0) ? x1.x : (u == 1) ? x1.y : (u == 2) ? x1.z : x1.w;
            a0 = fmaf(xe0, gv, a0);  c0 = fmaf(xe0, rv, c0);
            a1 = fmaf(xe1, gv, a1);  c1 = fmaf(xe1, rv, c1);
        }
    }
    a0 *= -L2E; c0 *= -L2E; a1 *= -L2E; c1 *= -L2E;
    glN[(size_t)t0 * 32 + i] = a0;  rlN[(size_t)t0 * 32 + i] = c0;
    glN[(size_t)t1 * 32 + i] = a1;  rlN[(size_t)t1 * 32 + i] = c1;
    if (wsgl) {
#pragma unroll
        for (int u = 0; u < 2; ++u) {
            int t = u ? t1 : t0;
            float a = u ? a1 : a0, c = u ? c1 : c0;
            int m  = t % SEG;
            int s1 = t / SEG + 1;
            if (m >= SEG - WARM && s1 < NSEG) {
                size_t o = ((size_t)s1 * WARM + (m - (SEG - WARM))) * SDIM + i;
                wsgl[o] = a;  wsrl[o] = c;
            }
            if (t < WARM) {                    // window 0 (dummy, seg 0)
                size_t o = (size_t)t * SDIM + i;
                wsgl[o] = a;  wsrl[o] = c;
            }
        }
    }
}

// DPP helpers
#define DPP_ADD(S_, CTRL_)                                                     \
{   int t__ = __builtin_amdgcn_update_dpp(0, __builtin_bit_cast(int, (S_)),    \
                                          (CTRL_), 0xF, 0xF, true);            \
    (S_) += __builtin_bit_cast(float, t__); }
#define HALFSUM(S_)                                                            \
    DPP_ADD(S_, 0x111) DPP_ADD(S_, 0x112) DPP_ADD(S_, 0x114)                   \
    DPP_ADD(S_, 0x118) DPP_ADD(S_, 0x142)
// wave_ror:1 (0x13C): lane l <- lane (l-1)&63 (same direction family as the
// validated row_shr in HALFSUM). Mirrored 32-state vectors rotate correctly.
#define ROR1(X_)                                                               \
{   int t__ = __builtin_amdgcn_update_dpp(0, __builtin_bit_cast(int, (X_)),    \
                                          0x13C, 0xF, 0xF, true);              \
    (X_) = __builtin_bit_cast(float, t__); }

// ---------------------------------------------------------------------------
// STEP4: 4 chains, MIRRORED state (lane i & i+32 hold state i of every chain).
// Zero LDS: W1/W2 matvecs run on DPP wave-rotations with load-time-permuted
// weights; the only cross-lane non-DPP op is one shfl_xor(32) per chain (W2
// half-combine). Stores/sigma are half-multiplexed (half0: chains A,B;
// half1: C,D) since mirror copies are identical.
// ---------------------------------------------------------------------------
#define STEP4(TIA_, TIB_, TIC_, TID_, GA_, LA_, GB_, LB_, GC_, LC_, GD_, LD_,  \
              RA_, RB_, RC_, RD_, DOSTORE_)                                    \
{                                                                              \
    const int tiA_ = (TIA_); const int tiB_ = (TIB_);                          \
    const int tiC_ = (TIC_); const int tiD_ = (TID_);                          \
    float rotA_ = __builtin_amdgcn_rcpf(                                       \
        1.f + __builtin_amdgcn_exp2f(fmaf(rswN, vA, (LA_)))) * vA;             \
    float rotB_ = __builtin_amdgcn_rcpf(                                       \
        1.f + __builtin_amdgcn_exp2f(fmaf(rswN, vB, (LB_)))) * vB;             \
    float rotC_ = __builtin_amdgcn_rcpf(                                       \
        1.f + __builtin_amdgcn_exp2f(fmaf(rswN, vC, (LC_)))) * vC;             \
    float rotD_ = __builtin_amdgcn_rcpf(                                       \
        1.f + __builtin_amdgcn_exp2f(fmaf(rswN, vD, (LD_)))) * vD;             \
    float zgA_ = fmaf(gswN, vA, (GA_));                                        \
    float zgB_ = fmaf(gswN, vB, (GB_));                                        \
    float zgC_ = fmaf(gswN, vC, (GC_));                                        \
    float zgD_ = fmaf(gswN, vD, (GD_));                                        \
    float hA_ = fmaf(w1f0, (RA_), b1l);                                        \
    float hB_ = fmaf(w1f0, (RB_), b1l);                                        \
    float hC_ = fmaf(w1f0, (RC_), b1l);                                        \
    float hD_ = fmaf(w1f0, (RD_), b1l);                                        \
    hA_ = fmaf(w1f1, fabsf((RA_)), hA_);                                       \
    hB_ = fmaf(w1f1, fabsf((RB_)), hB_);                                       \
    hC_ = fmaf(w1f1, fabsf((RC_)), hC_);                                       \
    hD_ = fmaf(w1f1, fabsf((RD_)), hD_);                                       \
    hA_ = fmaf(w1f2, (RA_) * (RA_), hA_);                                      \
    hB_ = fmaf(w1f2, (RB_) * (RB_), hB_);                                      \
    hC_ = fmaf(w1f2, (RC_) * (RC_), hC_);                                      \
    hD_ = fmaf(w1f2, (RD_) * (RD_), hD_);                                      \
    _Pragma("unroll")                                                          \
    for (int s_ = 0; s_ < 32; ++s_) {                                          \
        hA_ = fmaf(w1rot[s_], rotA_, hA_);                                     \
        hB_ = fmaf(w1rot[s_], rotB_, hB_);                                     \
        hC_ = fmaf(w1rot[s_], rotC_, hC_);                                     \
        hD_ = fmaf(w1rot[s_], rotD_, hD_);                                     \
        if (s_ != 31) { ROR1(rotA_) ROR1(rotB_) ROR1(rotC_) ROR1(rotD_) }      \
    }                                                                          \
    float thA_ = fmaf(-2.f, __builtin_amdgcn_rcpf(                             \
                   __builtin_amdgcn_exp2f(hA_) + 1.f), 1.f);                   \
    float thB_ = fmaf(-2.f, __builtin_amdgcn_rcpf(                             \
                   __builtin_amdgcn_exp2f(hB_) + 1.f), 1.f);                   \
    float thC_ = fmaf(-2.f, __builtin_amdgcn_rcpf(                             \
                   __builtin_amdgcn_exp2f(hC_) + 1.f), 1.f);                   \
    float thD_ = fmaf(-2.f, __builtin_amdgcn_rcpf(                             \
                   __builtin_amdgcn_exp2f(hD_) + 1.f), 1.f);                   \
    float pA_ = 0.f, pB_ = 0.f, pC_ = 0.f, pD_ = 0.f;                          \
    _Pragma("unroll")                                                          \
    for (int s_ = 0; s_ < 32; ++s_) {                                          \
        pA_ = fmaf(w2rot[s_], thA_, pA_);                                      \
        pB_ = fmaf(w2rot[s_], thB_, pB_);                                      \
        pC_ = fmaf(w2rot[s_], thC_, pC_);                                      \
        pD_ = fmaf(w2rot[s_], thD_, pD_);                                      \
        if (s_ != 31) { ROR1(thA_) ROR1(thB_) ROR1(thC_) ROR1(thD_) }          \
    }                                                                          \
    pA_ += __shfl_xor(pA_, 32);                                                \
    pB_ += __shfl_xor(pB_, 32);                                                \
    pC_ += __shfl_xor(pC_, 32);                                                \
    pD_ += __shfl_xor(pD_, 32);                                                \
    float zA_ = __builtin_amdgcn_rcpf(1.f + __builtin_amdgcn_exp2f(zgA_));     \
    float zB_ = __builtin_amdgcn_rcpf(1.f + __builtin_amdgcn_exp2f(zgB_));     \
    float zC_ = __builtin_amdgcn_rcpf(1.f + __builtin_amdgcn_exp2f(zgC_));     \
    float zD_ = __builtin_amdgcn_rcpf(1.f + __builtin_amdgcn_exp2f(zgD_));     \
    float rawA_ = pA_ + b2l;                                                   \
    float rawB_ = pB_ + b2l;                                                   \
    float rawC_ = pC_ + b2l;                                                   \
    float rawD_ = pD_ + b2l;                                                   \
    float candA_ = LN2 * (fmaxf(rawA_, 0.f) + __builtin_amdgcn_logf(           \
                   1.f + __builtin_amdgcn_exp2f(-fabsf(rawA_))));              \
    float candB_ = LN2 * (fmaxf(rawB_, 0.f) + __builtin_amdgcn_logf(           \
                   1.f + __builtin_amdgcn_exp2f(-fabsf(rawB_))));              \
    float candC_ = LN2 * (fmaxf(rawC_, 0.f) + __builtin_amdgcn_logf(           \
                   1.f + __builtin_amdgcn_exp2f(-fabsf(rawC_))));              \
    float candD_ = LN2 * (fmaxf(rawD_, 0.f) + __builtin_amdgcn_logf(           \
                   1.f + __builtin_amdgcn_exp2f(-fabsf(rawD_))));              \
    float vnA_ = fmaxf(fmaf(zA_, candA_ - vA, vA), EPSV);                      \
    float vnB_ = fmaxf(fmaf(zB_, candB_ - vB, vB), EPSV);                      \
    float vnC_ = fmaxf(fmaf(zC_, candC_ - vC, vC), EPSV);                      \
    float vnD_ = fmaxf(fmaf(zD_, candD_ - vD, vD), EPSV);                      \
    if (DOSTORE_) {                                                            \
        int t1s_ = half ? tiC_ : tiA_;                                         \
        int t2s_ = half ? tiD_ : tiB_;                                         \
        out_z  [(size_t)t1s_ * SDIM + i] = half ? zC_ : zA_;                   \
        out_cand[(size_t)t1s_ * SDIM + i] = half ? candC_ : candA_;            \
        out_z  [(size_t)t2s_ * SDIM + i] = half ? zD_ : zB_;                   \
        out_cand[(size_t)t2s_ * SDIM + i] = half ? candD_ : candB_;            \
        float sA_ = vnA_, sB_ = vnB_, sC_ = vnC_, sD_ = vnD_;                  \
        HALFSUM(sA_) HALFSUM(sB_) HALFSUM(sC_) HALFSUM(sD_)                    \
        if ((lane & 31) == 31) {                                               \
            out_sigma[t1s_] = (half ? sC_ : sA_) * (1.f / 32.f);               \
            out_sigma[t2s_] = (half ? sD_ : sB_) * (1.f / 32.f);               \
        }                                                                      \
    }                                                                          \
    vA = vnA_;  vB = vnB_;  vC = vnC_;  vD = vnD_;                             \
}

// 4-deep pipelined quad-chain run (mirrored: every lane loads all 4 chains'
// gl/rl at [t*32 + i]; r loaded float4 per chain per 4-step group).
#define PIPE4(GAP_, LAP_, GBP_, LBP_, GCP_, LCP_, GDP_, LDP_,                  \
              RAP_, RBP_, RCP_, RDP_, NSTEPS_, TA_, TB_, TC_, TD_, DOSTORE_)   \
{                                                                              \
    float gq_[4][4], lq_[4][4];                                                \
    _Pragma("unroll")                                                          \
    for (int k_ = 0; k_ < 4; ++k_) {                                           \
        gq_[0][k_] = (GAP_)[(size_t)k_ * SDIM + i];                            \
        lq_[0][k_] = (LAP_)[(size_t)k_ * SDIM + i];                            \
        gq_[1][k_] = (GBP_)[(size_t)k_ * SDIM + i];                            \
        lq_[1][k_] = (LBP_)[(size_t)k_ * SDIM + i];                            \
        gq_[2][k_] = (GCP_)[(size_t)k_ * SDIM + i];                            \
        lq_[2][k_] = (LCP_)[(size_t)k_ * SDIM + i];                            \
        gq_[3][k_] = (GDP_)[(size_t)k_ * SDIM + i];                            \
        lq_[3][k_] = (LDP_)[(size_t)k_ * SDIM + i];                            \
    }                                                                          \
    float4 rA4_ = *(const float4*)(RAP_);                                      \
    float4 rB4_ = *(const float4*)(RBP_);                                      \
    float4 rC4_ = *(const float4*)(RCP_);                                      \
    float4 rD4_ = *(const float4*)(RDP_);                                      \
    for (int s_ = 0; s_ < (NSTEPS_); s_ += 4) {                                \
        int rp_ = s_ + 4; if (rp_ > (NSTEPS_) - 4) rp_ = (NSTEPS_) - 4;        \
        float4 rAn_ = *(const float4*)((RAP_) + rp_);                          \
        float4 rBn_ = *(const float4*)((RBP_) + rp_);                          \
        float4 rCn_ = *(const float4*)((RCP_) + rp_);                          \
        float4 rDn_ = *(const float4*)((RDP_) + rp_);                          \
        _Pragma("unroll")                                                      \
        for (int k_ = 0; k_ < 4; ++k_) {                                       \
            int tp_ = s_ + 4 + k_;                                             \
            if (tp_ > (NSTEPS_) - 1) tp_ = (NSTEPS_) - 1;                      \
            float cga_ = gq_[0][k_], cla_ = lq_[0][k_];                        \
            float cgb_ = gq_[1][k_], clb_ = lq_[1][k_];                        \
            float cgc_ = gq_[2][k_], clc_ = lq_[2][k_];                        \
            float cgd_ = gq_[3][k_], cld_ = lq_[3][k_];                        \
            gq_[0][k_] = (GAP_)[(size_t)tp_ * SDIM + i];                       \
            lq_[0][k_] = (LAP_)[(size_t)tp_ * SDIM + i];                       \
            gq_[1][k_] = (GBP_)[(size_t)tp_ * SDIM + i];                       \
            lq_[1][k_] = (LBP_)[(size_t)tp_ * SDIM + i];                       \
            gq_[2][k_] = (GCP_)[(size_t)tp_ * SDIM + i];                       \
            lq_[2][k_] = (LCP_)[(size_t)tp_ * SDIM + i];                       \
            gq_[3][k_] = (GDP_)[(size_t)tp_ * SDIM + i];                       \
            lq_[3][k_] = (LDP_)[(size_t)tp_ * SDIM + i];                       \
            float ra_ = (k_ == 0) ? rA4_.x : (k_ == 1) ? rA4_.y                \
                       : (k_ == 2) ? rA4_.z : rA4_.w;                          \
            float rb_ = (k_ == 0) ? rB4_.x : (k_ == 1) ? rB4_.y                \
                       : (k_ == 2) ? rB4_.z : rB4_.w;                          \
            float rc_ = (k_ == 0) ? rC4_.x : (k_ == 1) ? rC4_.y                \
                       : (k_ == 2) ? rC4_.z : rC4_.w;                          \
            float rd_ = (k_ == 0) ? rD4_.x : (k_ == 1) ? rD4_.y                \
                       : (k_ == 2) ? rD4_.z : rD4_.w;                          \
            STEP4((TA_) + s_ + k_, (TB_) + s_ + k_,                            \
                  (TC_) + s_ + k_, (TD_) + s_ + k_,                            \
                  cga_, cla_, cgb_, clb_, cgc_, clc_, cgd_, cld_,              \
                  ra_, rb_, rc_, rd_, DOSTORE_)                                \
        }                                                                      \
        rA4_ = rAn_; rB4_ = rBn_; rC4_ = rCn_; rD4_ = rDn_;                    \
    }                                                                          \
}

// ---------------------------------------------------------------------------
// Kernel 2: speculative-parallel scan, 4 mirrored chains per wave, LDS-free
// inner step (DS-pipe bottleneck from round 10 removed).
// ---------------------------------------------------------------------------
__global__ void __launch_bounds__(64)
__attribute__((amdgpu_waves_per_eu(1, 1)))
scan_kernel(const float* __restrict__ returns,
            const float* __restrict__ gsw,
            const float* __restrict__ rsw,
            const float* __restrict__ W1,     // [64, 35]
            const float* __restrict__ b1,     // [64]
            const float* __restrict__ W2,     // [32, 64]
            const float* __restrict__ b2,     // [32]
            const float* __restrict__ X,      // fallback warm-up only
            const float* __restrict__ gb,
            const float* __restrict__ rg,
            const float* __restrict__ wsgl,   // warm windows (or null)
            const float* __restrict__ wsrl,
            float* __restrict__ out_sigma,    // [N]
            float* __restrict__ out_z,        // [N*32]  (pre-filled glN)
            float* __restrict__ out_cand,     // [N*32]  (pre-filled rlN)
            float* __restrict__ out_vfinal)   // [32]
{
    const int lane = threadIdx.x;
    const int i    = lane & 31;
    const int half = lane >> 5;
    const int bid  = blockIdx.x;
    const int tA   = (4 * bid) * SEG;
    const int tB   = tA + SEG;
    const int tC   = tA + 2 * SEG;
    const int tD   = tA + 3 * SEG;
    const int wstA = (tA == 0) ? 0 : (tA - WARM);
    const int wstB = tB - WARM;
    const int wstC = tC - WARM;
    const int wstD = tD - WARM;

    __shared__ __align__(16) float smGB[32 * 32];   // fallback only
    __shared__ __align__(16) float smRG[32 * 32];   // fallback only

    // ---- weights, pre-scaled AND pre-permuted for the DPP rotation ----
    float gswN = -L2E * gsw[i];
    float rswN = -L2E * rsw[i];
    float w1f0 = (2.f * L2E) * W1[lane * 35 + 0];
    float w1f1 = (2.f * L2E) * W1[lane * 35 + 1];
    float w1f2 = (2.f * L2E) * W1[lane * 35 + 2];
    float w1rot[32];   // step s: rot holds rv[(lane-s)&31] -> weight col (lane-s)&31
#pragma unroll
    for (int s = 0; s < 32; ++s)
        w1rot[s] = (2.f * L2E) * W1[lane * 35 + 3 + ((lane - s) & 31)];
    float b1l = (2.f * L2E) * b1[lane];
    float w2rot[32];   // step s: th holds th[(lane-s)&63] -> W2[i][(lane-s)&63]
#pragma unroll
    for (int s = 0; s < 32; ++s)
        w2rot[s] = L2E * W2[i * 64 + ((lane - s) & 63)];
    float b2l = L2E * b2[i];

    PIN(gswN); PIN(rswN); PIN(b1l); PIN(b2l);
    PIN(w1f0); PIN(w1f1); PIN(w1f2);
#pragma unroll
    for (int s = 0; s < 32; ++s) { PIN(w1rot[s]); PIN(w2rot[s]); }

    // ---- initial states (wave-uniform guesses; converge during warm-up) ----
    float rA0 = returns[wstA];
    float rB0 = returns[wstB];
    float rC0 = returns[wstC];
    float rD0 = returns[wstD];
    float vA = rA0 * rA0;
    float vB = rB0 * rB0;
    float vC = rC0 * rC0;
    float vD = rD0 * rD0;

    // ---- warm-up (4 chains fused) ----
    if (wsgl) {
        const float* gA = wsgl + (size_t)(4 * bid + 0) * WARM * SDIM;
        const float* lA = wsrl + (size_t)(4 * bid + 0) * WARM * SDIM;
        const float* gB = wsgl + (size_t)(4 * bid + 1) * WARM * SDIM;
        const float* lB = wsrl + (size_t)(4 * bid + 1) * WARM * SDIM;
        const float* gC = wsgl + (size_t)(4 * bid + 2) * WARM * SDIM;
        const float* lC = wsrl + (size_t)(4 * bid + 2) * WARM * SDIM;
        const float* gD = wsgl + (size_t)(4 * bid + 3) * WARM * SDIM;
        const float* lD = wsrl + (size_t)(4 * bid + 3) * WARM * SDIM;
        PIPE4(gA, lA, gB, lB, gC, lC, gD, lD,
              returns + wstA, returns + wstB, returns + wstC, returns + wstD,
              WARM, 0, 0, 0, 0, false)
    } else {
        // cold fallback (never taken when ws present): recompute gl/rl from X
        for (int k = lane; k < 1024; k += 64) {
            smGB[k] = -L2E * gb[k];
            smRG[k] = -L2E * rg[k];
        }
        __syncthreads();
        for (int t = 0; t < WARM; ++t) {
            float ga[4], la[4];
            const int ws4[4] = { wstA, wstB, wstC, wstD };
#pragma unroll
            for (int c = 0; c < 4; ++c) {
                const float* xr = X + (size_t)(ws4[c] + t) * 32;
                float a_ = 0.f, c_ = 0.f;
#pragma unroll
                for (int j = 0; j < 32; ++j) {
                    float xe = xr[j];
                    a_ = fmaf(xe, smGB[j * 32 + i], a_);
                    c_ = fmaf(xe, smRG[j * 32 + i], c_);
                }
                ga[c] = a_;  la[c] = c_;
            }
            float ra_ = returns[wstA + t], rb_ = returns[wstB + t];
            float rc_ = returns[wstC + t], rd_ = returns[wstD + t];
            STEP4(0, 0, 0, 0, ga[0], la[0], ga[1], la[1],
                  ga[2], la[2], ga[3], la[3], ra_, rb_, rc_, rd_, false)
        }
    }

    // chain A of block 0 starts exactly (its dummy warm-up is discarded)
    if (tA == 0) {
        float r0 = returns[0];
        vA = r0 * r0;
    }

    // ---- owned segments (reads clamped to own range; overwrite in place) ----
    {
        PIPE4(out_z   + (size_t)tA * SDIM, out_cand + (size_t)tA * SDIM,
              out_z   + (size_t)tB * SDIM, out_cand + (size_t)tB * SDIM,
              out_z   + (size_t)tC * SDIM, out_cand + (size_t)tC * SDIM,
              out_z   + (size_t)tD * SDIM, out_cand + (size_t)tD * SDIM,
              returns + tA, returns + tB, returns + tC, returns + tD,
              SEG, tA, tB, tC, tD, true)
    }

    // final state = end of chain D of the last block (mirrored; half0 stores)
    if (bid == NBLK - 1 && lane < SDIM) out_vfinal[i] = vD;
}

// ---------------------------------------------------------------------------
extern "C" void kernel_launch(void* const* d_in, const int* in_sizes, int n_in,
                              void* d_out, int out_size, void* d_ws, size_t ws_size,
                              hipStream_t stream)
{
    const float* X          = (const float*)d_in[0];
    const float* returns    = (const float*)d_in[1];
    const float* gate_beta  = (const float*)d_in[2];
    const float* gsw        = (const float*)d_in[3];
    const float* reset_gamma= (const float*)d_in[4];
    const float* rsw        = (const float*)d_in[5];
    const float* W1         = (const float*)d_in[6];
    const float* b1         = (const float*)d_in[7];
    const float* W2         = (const float*)d_in[8];
    const float* b2         = (const float*)d_in[9];

    float* out       = (float*)d_out;
    float* out_sigma = out;                                   // [N]
    float* out_z     = out + NT;                              // [N*S]
    float* out_cand  = out + NT + (size_t)NT * SDIM;          // [N*S]
    float* out_vfin  = out + NT + 2 * (size_t)NT * SDIM;      // [S]

    const bool use_ws = (ws_size >= WS_NEEDED);
    float* wsgl = use_ws ? (float*)d_ws : nullptr;
    float* wsrl = use_ws ? ((float*)d_ws + WSW) : nullptr;

    precompute_lin<<<(NT / 2 * SDIM) / 256, 256, 0, stream>>>(
        X, gate_beta, reset_gamma, out_z, out_cand, wsgl, wsrl);

    scan_kernel<<<NBLK, 64, 0, stream>>>(
        returns, gsw, rsw, W1, b1, W2, b2,
        X, gate_beta, reset_gamma, wsgl, wsrl,
        out_sigma, out_z, out_cand, out_vfin);
}

// Round 13
// 206.412 us; speedup vs baseline: 1.1043x; 1.1043x over previous
//
#include <hip/hip_runtime.h>

#define NT    262144
#define SDIM  32
#define NSEG  4096           // speculative segments; one WAVE runs TWO chains
#define SEG   (NT / NSEG)    // 64 steps per segment
#define WARM  48             // warm-up steps; WARM < SEG => warm windows disjoint
#define NBLK  (NSEG / 2)     // 2048 blocks -> 2 waves/SIMD (TLP fills bubbles)
#define EPSV  1e-12f
#define L2E   1.4426950408889634f   // log2(e)
#define LN2   0.6931471805599453f
// warm-window copies in d_ws: NSEG windows (window 0 = dummy) of WARM x 32
#define WSW   ((size_t)NSEG * WARM * SDIM)
#define WS_NEEDED (2 * WSW * 4)     // 50.3 MB, proven available rounds 6-11

#define PIN(X_) asm volatile("" : "+v"(X_))

// ---------------------------------------------------------------------------
// Kernel 1: gl/rl precompute (pre-negated-scaled for exp2 sigmoids) + compact
// warm-window copies (unchanged from rounds 10/11).
// ---------------------------------------------------------------------------
__global__ void precompute_lin(const float* __restrict__ X,
                               const float* __restrict__ gb,
                               const float* __restrict__ rg,
                               float* __restrict__ glN,
                               float* __restrict__ rlN,
                               float* __restrict__ wsgl,   // may be null
                               float* __restrict__ wsrl)
{
    int idx = blockIdx.x * blockDim.x + threadIdx.x;   // covers (NT/2)*32
    int t0 = idx >> 5, i = idx & 31;
    int t1 = t0 + NT / 2;
    const float4* xr0 = (const float4*)(X + (size_t)t0 * 32);
    const float4* xr1 = (const float4*)(X + (size_t)t1 * 32);
    float a0 = 0.f, c0 = 0.f, a1 = 0.f, c1 = 0.f;
#pragma unroll
    for (int q = 0; q < 8; ++q) {
        float4 x0 = xr0[q], x1 = xr1[q];
#pragma unroll
        for (int u = 0; u < 4; ++u) {
            int j = 4 * q + u;
            float gv = gb[j * 32 + i], rv = rg[j * 32 + i];
            float xe0 = (u == 0) ? x0.x : (u == 1) ? x0.y : (u == 2) ? x0.z : x0.w;
            float xe1 = (u == 0) ? x1.x : (u == 1) ? x1.y : (u == 2) ? x1.z : x1.w;
            a0 = fmaf(xe0, gv, a0);  c0 = fmaf(xe0, rv, c0);
            a1 = fmaf(xe1, gv, a1);  c1 = fmaf(xe1, rv, c1);
        }
    }
    a0 *= -L2E; c0 *= -L2E; a1 *= -L2E; c1 *= -L2E;
    glN[(size_t)t0 * 32 + i] = a0;  rlN[(size_t)t0 * 32 + i] = c0;
    glN[(size_t)t1 * 32 + i] = a1;  rlN[(size_t)t1 * 32 + i] = c1;
    if (wsgl) {
#pragma unroll
        for (int u = 0; u < 2; ++u) {
            int t = u ? t1 : t0;
            float a = u ? a1 : a0, c = u ? c1 : c0;
            int m  = t % SEG;
            int s1 = t / SEG + 1;
            if (m >= SEG - WARM && s1 < NSEG) {
                size_t o = ((size_t)s1 * WARM + (m - (SEG - WARM))) * SDIM + i;
                wsgl[o] = a;  wsrl[o] = c;
            }
            if (t < WARM) {                    // window 0 (dummy, seg 0)
                size_t o = (size_t)t * SDIM + i;
                wsgl[o] = a;  wsrl[o] = c;
            }
        }
    }
}

// DPP helpers (all validated r9-r11)
#define DPP_ADD(S_, CTRL_)                                                     \
{   int t__ = __builtin_amdgcn_update_dpp(0, __builtin_bit_cast(int, (S_)),    \
                                          (CTRL_), 0xF, 0xF, true);            \
    (S_) += __builtin_bit_cast(float, t__); }
#define HALFSUM(S_)                                                            \
    DPP_ADD(S_, 0x111) DPP_ADD(S_, 0x112) DPP_ADD(S_, 0x114)                   \
    DPP_ADD(S_, 0x118) DPP_ADD(S_, 0x142)
// wave_ror:1 : lane l <- lane (l-1)&63; mirrored 32-vectors rotate by 1.
#define ROR1(X_)                                                               \
{   int t__ = __builtin_amdgcn_update_dpp(0, __builtin_bit_cast(int, (X_)),    \
                                          0x13C, 0xF, 0xF, true);              \
    (X_) = __builtin_bit_cast(float, t__); }

// ---------------------------------------------------------------------------
// STEP2 (hybrid): 2 chains, MIRRORED state. W1 matvec = DPP wave-rotation
// (zero LDS, validated r11); W2 matvec = LDS th-broadcast half-dot +
// shfl_xor(32) combine (validated r9). Stores half-multiplexed.
// ---------------------------------------------------------------------------
#define STEP2(TIA_, TIB_, GA_, LA_, GB_, LB_, RA_, RB_, DOSTORE_)              \
{                                                                              \
    const int tiA_ = (TIA_); const int tiB_ = (TIB_);                          \
    float rotA_ = __builtin_amdgcn_rcpf(                                       \
        1.f + __builtin_amdgcn_exp2f(fmaf(rswN, vA, (LA_)))) * vA;             \
    float rotB_ = __builtin_amdgcn_rcpf(                                       \
        1.f + __builtin_amdgcn_exp2f(fmaf(rswN, vB, (LB_)))) * vB;             \
    float zgA_ = fmaf(gswN, vA, (GA_));                                        \
    float zgB_ = fmaf(gswN, vB, (GB_));                                        \
    float hA_ = fmaf(w1f0, (RA_), b1l);                                        \
    float hB_ = fmaf(w1f0, (RB_), b1l);                                        \
    hA_ = fmaf(w1f1, fabsf((RA_)), hA_);                                       \
    hB_ = fmaf(w1f1, fabsf((RB_)), hB_);                                       \
    hA_ = fmaf(w1f2, (RA_) * (RA_), hA_);                                      \
    hB_ = fmaf(w1f2, (RB_) * (RB_), hB_);                                      \
    _Pragma("unroll")                                                          \
    for (int s_ = 0; s_ < 32; ++s_) {                                          \
        hA_ = fmaf(w1rot[s_], rotA_, hA_);                                     \
        hB_ = fmaf(w1rot[s_], rotB_, hB_);                                     \
        if (s_ != 31) { ROR1(rotA_) ROR1(rotB_) }                              \
    }                                                                          \
    float thA_ = fmaf(-2.f, __builtin_amdgcn_rcpf(                             \
                   __builtin_amdgcn_exp2f(hA_) + 1.f), 1.f);                   \
    float thB_ = fmaf(-2.f, __builtin_amdgcn_rcpf(                             \
                   __builtin_amdgcn_exp2f(hB_) + 1.f), 1.f);                   \
    smB[lane] = thA_;                                                          \
    smB[64 + lane] = thB_;                                                     \
    __builtin_amdgcn_wave_barrier();                                           \
    float zA_ = __builtin_amdgcn_rcpf(1.f + __builtin_amdgcn_exp2f(zgA_));     \
    float zB_ = __builtin_amdgcn_rcpf(1.f + __builtin_amdgcn_exp2f(zgB_));     \
    float qa0_ = 0.f, qa1_ = 0.f, qa2_ = 0.f, qa3_ = 0.f;                      \
    float qb0_ = 0.f, qb1_ = 0.f, qb2_ = 0.f, qb3_ = 0.f;                      \
    {                                                                          \
        const float4* pa_ = (const float4*)(smB + (half << 5));                \
        const float4* pb_ = (const float4*)(smB + 64 + (half << 5));           \
        _Pragma("unroll")                                                      \
        for (int q_ = 0; q_ < 8; ++q_) {                                       \
            float4 ca_ = pa_[q_];                                              \
            qa0_ = fmaf(w2r[4 * q_ + 0], ca_.x, qa0_);                         \
            qa1_ = fmaf(w2r[4 * q_ + 1], ca_.y, qa1_);                         \
            qa2_ = fmaf(w2r[4 * q_ + 2], ca_.z, qa2_);                         \
            qa3_ = fmaf(w2r[4 * q_ + 3], ca_.w, qa3_);                         \
            float4 cb_ = pb_[q_];                                              \
            qb0_ = fmaf(w2r[4 * q_ + 0], cb_.x, qb0_);                         \
            qb1_ = fmaf(w2r[4 * q_ + 1], cb_.y, qb1_);                         \
            qb2_ = fmaf(w2r[4 * q_ + 2], cb_.z, qb2_);                         \
            qb3_ = fmaf(w2r[4 * q_ + 3], cb_.w, qb3_);                         \
        }                                                                      \
    }                                                                          \
    __builtin_amdgcn_wave_barrier();                                           \
    float pA_ = (qa0_ + qa1_) + (qa2_ + qa3_);                                 \
    float pB_ = (qb0_ + qb1_) + (qb2_ + qb3_);                                 \
    pA_ += __shfl_xor(pA_, 32);                                                \
    pB_ += __shfl_xor(pB_, 32);                                                \
    float rawA_ = pA_ + b2l;                                                   \
    float rawB_ = pB_ + b2l;                                                   \
    float candA_ = LN2 * (fmaxf(rawA_, 0.f) + __builtin_amdgcn_logf(           \
                   1.f + __builtin_amdgcn_exp2f(-fabsf(rawA_))));              \
    float candB_ = LN2 * (fmaxf(rawB_, 0.f) + __builtin_amdgcn_logf(           \
                   1.f + __builtin_amdgcn_exp2f(-fabsf(rawB_))));              \
    float vnA_ = fmaxf(fmaf(zA_, candA_ - vA, vA), EPSV);                      \
    float vnB_ = fmaxf(fmaf(zB_, candB_ - vB, vB), EPSV);                      \
    if (DOSTORE_) {                                                            \
        int ts_ = half ? tiB_ : tiA_;                                          \
        out_z  [(size_t)ts_ * SDIM + i] = half ? zB_ : zA_;                    \
        out_cand[(size_t)ts_ * SDIM + i] = half ? candB_ : candA_;             \
        float sA_ = vnA_, sB_ = vnB_;                                          \
        HALFSUM(sA_) HALFSUM(sB_)                                              \
        if ((lane & 31) == 31) {                                               \
            out_sigma[ts_] = (half ? sB_ : sA_) * (1.f / 32.f);                \
        }                                                                      \
    }                                                                          \
    vA = vnA_;  vB = vnB_;                                                     \
}

// 4-deep pipelined dual-chain run (mirrored loads at [t*32 + i]).
#define PIPE2(GAP_, LAP_, GBP_, LBP_, RAP_, RBP_, NSTEPS_, TA_, TB_, DOSTORE_) \
{                                                                              \
    float gqa_[4], lqa_[4], gqb_[4], lqb_[4];                                  \
    _Pragma("unroll")                                                          \
    for (int k_ = 0; k_ < 4; ++k_) {                                           \
        gqa_[k_] = (GAP_)[(size_t)k_ * SDIM + i];                              \
        lqa_[k_] = (LAP_)[(size_t)k_ * SDIM + i];                              \
        gqb_[k_] = (GBP_)[(size_t)k_ * SDIM + i];                              \
        lqb_[k_] = (LBP_)[(size_t)k_ * SDIM + i];                              \
    }                                                                          \
    float4 rA4_ = *(const float4*)(RAP_);                                      \
    float4 rB4_ = *(const float4*)(RBP_);                                      \
    for (int s_ = 0; s_ < (NSTEPS_); s_ += 4) {                                \
        int rp_ = s_ + 4; if (rp_ > (NSTEPS_) - 4) rp_ = (NSTEPS_) - 4;        \
        float4 rAn_ = *(const float4*)((RAP_) + rp_);                          \
        float4 rBn_ = *(const float4*)((RBP_) + rp_);                          \
        _Pragma("unroll")                                                      \
        for (int k_ = 0; k_ < 4; ++k_) {                                       \
            int tp_ = s_ + 4 + k_;                                             \
            if (tp_ > (NSTEPS_) - 1) tp_ = (NSTEPS_) - 1;                      \
            float cga_ = gqa_[k_], cla_ = lqa_[k_];                            \
            float cgb_ = gqb_[k_], clb_ = lqb_[k_];                            \
            gqa_[k_] = (GAP_)[(size_t)tp_ * SDIM + i];                         \
            lqa_[k_] = (LAP_)[(size_t)tp_ * SDIM + i];                         \
            gqb_[k_] = (GBP_)[(size_t)tp_ * SDIM + i];                         \
            lqb_[k_] = (LBP_)[(size_t)tp_ * SDIM + i];                         \
            float ra_ = (k_ == 0) ? rA4_.x : (k_ == 1) ? rA4_.y                \
                       : (k_ == 2) ? rA4_.z : rA4_.w;                          \
            float rb_ = (k_ == 0) ? rB4_.x : (k_ == 1) ? rB4_.y                \
                       : (k_ == 2) ? rB4_.z : rB4_.w;                          \
            STEP2((TA_) + s_ + k_, (TB_) + s_ + k_,                            \
                  cga_, cla_, cgb_, clb_, ra_, rb_, DOSTORE_)                  \
        }                                                                      \
        rA4_ = rAn_; rB4_ = rBn_;                                              \
    }                                                                          \
}

// ---------------------------------------------------------------------------
// Kernel 2: speculative-parallel scan, 2 chains/wave, 2048 waves
// (2 waves/SIMD). waves_per_eu(2,2): 256-reg budget (usage ~150 fits) AND
// occupancy 2 -> TLP fills DPP-hazard + transcendental bubbles.
// ---------------------------------------------------------------------------
__global__ void __launch_bounds__(64)
__attribute__((amdgpu_waves_per_eu(2, 2)))
scan_kernel(const float* __restrict__ returns,
            const float* __restrict__ gsw,
            const float* __restrict__ rsw,
            const float* __restrict__ W1,     // [64, 35]
            const float* __restrict__ b1,     // [64]
            const float* __restrict__ W2,     // [32, 64]
            const float* __restrict__ b2,     // [32]
            const float* __restrict__ X,      // fallback warm-up only
            const float* __restrict__ gb,
            const float* __restrict__ rg,
            const float* __restrict__ wsgl,   // warm windows (or null)
            const float* __restrict__ wsrl,
            float* __restrict__ out_sigma,    // [N]
            float* __restrict__ out_z,        // [N*32]  (pre-filled glN)
            float* __restrict__ out_cand,     // [N*32]  (pre-filled rlN)
            float* __restrict__ out_vfinal)   // [32]
{
    const int lane = threadIdx.x;
    const int i    = lane & 31;
    const int half = lane >> 5;
    const int bid  = blockIdx.x;
    const int tA   = (2 * bid) * SEG;
    const int tB   = tA + SEG;
    const int wstA = (tA == 0) ? 0 : (tA - WARM);
    const int wstB = tB - WARM;

    __shared__ __align__(16) float smB[128];        // th broadcast (2 chains)
    __shared__ __align__(16) float smGB[32 * 32];   // fallback only
    __shared__ __align__(16) float smRG[32 * 32];   // fallback only

    // ---- weights, pre-scaled; W1 pre-permuted for the DPP rotation ----
    float gswN = -L2E * gsw[i];
    float rswN = -L2E * rsw[i];
    float w1f0 = (2.f * L2E) * W1[lane * 35 + 0];
    float w1f1 = (2.f * L2E) * W1[lane * 35 + 1];
    float w1f2 = (2.f * L2E) * W1[lane * 35 + 2];
    float w1rot[32];   // step s: rot holds rv[(lane-s)&31] -> col (lane-s)&31
#pragma unroll
    for (int s = 0; s < 32; ++s)
        w1rot[s] = (2.f * L2E) * W1[lane * 35 + 3 + ((lane - s) & 31)];
    float b1l = (2.f * L2E) * b1[lane];
    float w2r[32];     // half-dot: cols (half*32)..+31 of row i
#pragma unroll
    for (int j = 0; j < 32; ++j) w2r[j] = L2E * W2[i * 64 + (half << 5) + j];
    float b2l = L2E * b2[i];

    PIN(gswN); PIN(rswN); PIN(b1l); PIN(b2l);
    PIN(w1f0); PIN(w1f1); PIN(w1f2);
#pragma unroll
    for (int s = 0; s < 32; ++s) { PIN(w1rot[s]); PIN(w2r[s]); }

    // ---- initial states (wave-uniform guesses; converge during warm-up) ----
    float rA0 = returns[wstA];
    float rB0 = returns[wstB];
    float vA = rA0 * rA0;
    float vB = rB0 * rB0;

    // ---- warm-up (both chains fused) ----
    if (wsgl) {
        const float* gA = wsgl + (size_t)(2 * bid + 0) * WARM * SDIM;
        const float* lA = wsrl + (size_t)(2 * bid + 0) * WARM * SDIM;
        const float* gB = wsgl + (size_t)(2 * bid + 1) * WARM * SDIM;
        const float* lB = wsrl + (size_t)(2 * bid + 1) * WARM * SDIM;
        PIPE2(gA, lA, gB, lB, returns + wstA, returns + wstB,
              WARM, 0, 0, false)
    } else {
        // cold fallback (never taken when ws present): recompute gl/rl from X
        for (int k = lane; k < 1024; k += 64) {
            smGB[k] = -L2E * gb[k];
            smRG[k] = -L2E * rg[k];
        }
        __syncthreads();
        for (int t = 0; t < WARM; ++t) {
            const float* x1 = X + (size_t)(wstA + t) * 32;
            const float* x2 = X + (size_t)(wstB + t) * 32;
            float a1 = 0.f, c1 = 0.f, a2 = 0.f, c2 = 0.f;
#pragma unroll
            for (int j = 0; j < 32; ++j) {
                float g_ = smGB[j * 32 + i], r_ = smRG[j * 32 + i];
                float xe1 = x1[j], xe2 = x2[j];
                a1 = fmaf(xe1, g_, a1);  c1 = fmaf(xe1, r_, c1);
                a2 = fmaf(xe2, g_, a2);  c2 = fmaf(xe2, r_, c2);
            }
            float ra_ = returns[wstA + t], rb_ = returns[wstB + t];
            STEP2(0, 0, a1, c1, a2, c2, ra_, rb_, false)
        }
    }

    // chain A of block 0 starts exactly (its dummy warm-up is discarded)
    if (tA == 0) {
        float r0 = returns[0];
        vA = r0 * r0;
    }

    // ---- owned segments (reads clamped to own range; overwrite in place) ----
    {
        PIPE2(out_z   + (size_t)tA * SDIM, out_cand + (size_t)tA * SDIM,
              out_z   + (size_t)tB * SDIM, out_cand + (size_t)tB * SDIM,
              returns + tA, returns + tB, SEG, tA, tB, true)
    }

    // final state = end of chain B of the last block (mirrored; half0 stores)
    if (bid == NBLK - 1 && lane < SDIM) out_vfinal[i] = vB;
}

// ---------------------------------------------------------------------------
extern "C" void kernel_launch(void* const* d_in, const int* in_sizes, int n_in,
                              void* d_out, int out_size, void* d_ws, size_t ws_size,
                              hipStream_t stream)
{
    const float* X          = (const float*)d_in[0];
    const float* returns    = (const float*)d_in[1];
    const float* gate_beta  = (const float*)d_in[2];
    const float* gsw        = (const float*)d_in[3];
    const float* reset_gamma= (const float*)d_in[4];
    const float* rsw        = (const float*)d_in[5];
    const float* W1         = (const float*)d_in[6];
    const float* b1         = (const float*)d_in[7];
    const float* W2         = (const float*)d_in[8];
    const float* b2         = (const float*)d_in[9];

    float* out       = (float*)d_out;
    float* out_sigma = out;                                   // [N]
    float* out_z     = out + NT;                              // [N*S]
    float* out_cand  = out + NT + (size_t)NT * SDIM;          // [N*S]
    float* out_vfin  = out + NT + 2 * (size_t)NT * SDIM;      // [S]

    const bool use_ws = (ws_size >= WS_NEEDED);
    float* wsgl = use_ws ? (float*)d_ws : nullptr;
    float* wsrl = use_ws ? ((float*)d_ws + WSW) : nullptr;

    precompute_lin<<<(NT / 2 * SDIM) / 256, 256, 0, stream>>>(
        X, gate_beta, reset_gamma, out_z, out_cand, wsgl, wsrl);

    scan_kernel<<<NBLK, 64, 0, stream>>>(
        returns, gsw, rsw, W1, b1, W2, b2,
        X, gate_beta, reset_gamma, wsgl, wsrl,
        out_sigma, out_z, out_cand, out_vfin);
}

// Round 17
// 183.219 us; speedup vs baseline: 1.2440x; 1.1266x over previous
//
#include <hip/hip_runtime.h>

#define NT    262144
#define SDIM  32
#define NSEG  4096           // speculative segments; ONE chain per wave
#define SEG   (NT / NSEG)    // 64 steps per segment
#define WARM  32             // warm-up steps (contraction margin: floor-stable 512->48)
#define NBLK  NSEG           // 4096 blocks -> 16 waves/CU (4/SIMD)
#define EPSV  1e-12f
#define L2E   1.4426950408889634f   // log2(e)
#define LN2   0.6931471805599453f
// warm-window copies in d_ws: NSEG windows (window 0 = dummy) of WARM x 32
#define WSW   ((size_t)NSEG * WARM * SDIM)
#define WS_NEEDED (2 * WSW * 4)     // 33.5 MB < 50.3 MB proven available

#define PIN(X_) asm volatile("" : "+v"(X_))

// ---------------------------------------------------------------------------
// Kernel 1: gl/rl precompute (pre-negated-scaled for exp2 sigmoids) + compact
// warm-window copies.
// ---------------------------------------------------------------------------
__global__ void precompute_lin(const float* __restrict__ X,
                               const float* __restrict__ gb,
                               const float* __restrict__ rg,
                               float* __restrict__ glN,
                               float* __restrict__ rlN,
                               float* __restrict__ wsgl,   // may be null
                               float* __restrict__ wsrl)
{
    int idx = blockIdx.x * blockDim.x + threadIdx.x;   // covers (NT/2)*32
    int t0 = idx >> 5, i = idx & 31;
    int t1 = t0 + NT / 2;
    const float4* xr0 = (const float4*)(X + (size_t)t0 * 32);
    const float4* xr1 = (const float4*)(X + (size_t)t1 * 32);
    float a0 = 0.f, c0 = 0.f, a1 = 0.f, c1 = 0.f;
#pragma unroll
    for (int q = 0; q < 8; ++q) {
        float4 x0 = xr0[q], x1 = xr1[q];
#pragma unroll
        for (int u = 0; u < 4; ++u) {
            int j = 4 * q + u;
            float gv = gb[j * 32 + i], rv = rg[j * 32 + i];
            float xe0 = (u == 0) ? x0.x : (u == 1) ? x0.y : (u == 2) ? x0.z : x0.w;
            float xe1 = (u == 0) ? x1.x : (u == 1) ? x1.y : (u == 2) ? x1.z : x1.w;
            a0 = fmaf(xe0, gv, a0);  c0 = fmaf(xe0, rv, c0);
            a1 = fmaf(xe1, gv, a1);  c1 = fmaf(xe1, rv, c1);
        }
    }
    a0 *= -L2E; c0 *= -L2E; a1 *= -L2E; c1 *= -L2E;
    glN[(size_t)t0 * 32 + i] = a0;  rlN[(size_t)t0 * 32 + i] = c0;
    glN[(size_t)t1 * 32 + i] = a1;  rlN[(size_t)t1 * 32 + i] = c1;
    if (wsgl) {
#pragma unroll
        for (int u = 0; u < 2; ++u) {
            int t = u ? t1 : t0;
            float a = u ? a1 : a0, c = u ? c1 : c0;
            int m  = t % SEG;
            int s1 = t / SEG + 1;
            if (m >= SEG - WARM && s1 < NSEG) {
                size_t o = ((size_t)s1 * WARM + (m - (SEG - WARM))) * SDIM + i;
                wsgl[o] = a;  wsrl[o] = c;
            }
            if (t < WARM) {                    // window 0 (dummy, seg 0)
                size_t o = (size_t)t * SDIM + i;
                wsgl[o] = a;  wsrl[o] = c;
            }
        }
    }
}

// DPP helpers (all validated r9-r13)
#define DPP_ADD(S_, CTRL_)                                                     \
{   int t__ = __builtin_amdgcn_update_dpp(0, __builtin_bit_cast(int, (S_)),    \
                                          (CTRL_), 0xF, 0xF, true);            \
    (S_) += __builtin_bit_cast(float, t__); }
#define HALFSUM(S_)                                                            \
    DPP_ADD(S_, 0x111) DPP_ADD(S_, 0x112) DPP_ADD(S_, 0x114)                   \
    DPP_ADD(S_, 0x118) DPP_ADD(S_, 0x142)
// wave_ror:1 : lane l <- lane (l-1)&63; mirrored 32-vectors rotate by 1.
#define ROR1(X_)                                                               \
{   int t__ = __builtin_amdgcn_update_dpp(0, __builtin_bit_cast(int, (X_)),    \
                                          0x13C, 0xF, 0xF, true);              \
    (X_) = __builtin_bit_cast(float, t__); }

// ---------------------------------------------------------------------------
// STEP1: ONE chain, MIRRORED state (lane i and i+32 hold state i). Pure-DPP
// step: W1 via wave-rotation with load-time-permuted weights (validated r11),
// W2 via wave-rotation over the 64 distinct th lanes + shfl_xor(32) combine
// (validated r11). ZERO LDS on the hot path -> nothing on the per-CU DS pipe;
// all work on the 4 replicated VALU pipes, bubbles filled by 4 waves/SIMD.
// ---------------------------------------------------------------------------
#define STEP1(TI_, GL_, RL_, RR_, DOSTORE_)                                    \
{                                                                              \
    const int ti_ = (TI_);                                                     \
    float rot_ = __builtin_amdgcn_rcpf(                                        \
        1.f + __builtin_amdgcn_exp2f(fmaf(rswN, v, (RL_)))) * v;               \
    float zg_ = fmaf(gswN, v, (GL_));                                          \
    float h_ = fmaf(w1f0, (RR_), b1l);                                         \
    h_ = fmaf(w1f1, fabsf((RR_)), h_);                                         \
    h_ = fmaf(w1f2, (RR_) * (RR_), h_);                                        \
    _Pragma("unroll")                                                          \
    for (int s_ = 0; s_ < 32; ++s_) {                                          \
        h_ = fmaf(w1rot[s_], rot_, h_);                                        \
        if (s_ != 31) { ROR1(rot_) }                                           \
    }                                                                          \
    float th_ = fmaf(-2.f, __builtin_amdgcn_rcpf(                              \
                   __builtin_amdgcn_exp2f(h_) + 1.f), 1.f);                    \
    float p_ = 0.f;                                                            \
    _Pragma("unroll")                                                          \
    for (int s_ = 0; s_ < 32; ++s_) {                                          \
        p_ = fmaf(w2rot[s_], th_, p_);                                         \
        if (s_ != 31) { ROR1(th_) }                                            \
    }                                                                          \
    p_ += __shfl_xor(p_, 32);                                                  \
    float z_ = __builtin_amdgcn_rcpf(1.f + __builtin_amdgcn_exp2f(zg_));       \
    float raw_ = p_ + b2l;                                                     \
    float cand_ = LN2 * (fmaxf(raw_, 0.f) + __builtin_amdgcn_logf(             \
                  1.f + __builtin_amdgcn_exp2f(-fabsf(raw_))));                \
    float vn_ = fmaxf(fmaf(z_, cand_ - v, v), EPSV);                           \
    if (DOSTORE_) {                                                            \
        out_z  [(size_t)ti_ * SDIM + i] = z_;   /* both halves: same value */  \
        out_cand[(size_t)ti_ * SDIM + i] = cand_;                              \
        float s_ = vn_;                                                        \
        HALFSUM(s_)                                                            \
        if (lane == 63) out_sigma[ti_] = s_ * (1.f / 32.f);                    \
    }                                                                          \
    v = vn_;                                                                   \
}

// 4-deep pipelined single-chain run (mirrored loads at [t*32 + i]).
#define PIPE1(GP_, LP_, RP_, NSTEPS_, TB_, DOSTORE_)                           \
{                                                                              \
    float gq_[4], lq_[4];                                                      \
    _Pragma("unroll")                                                          \
    for (int k_ = 0; k_ < 4; ++k_) {                                           \
        gq_[k_] = (GP_)[(size_t)k_ * SDIM + i];                                \
        lq_[k_] = (LP_)[(size_t)k_ * SDIM + i];                                \
    }                                                                          \
    float4 r4_ = *(const float4*)(RP_);                                        \
    for (int s_ = 0; s_ < (NSTEPS_); s_ += 4) {                                \
        int rp_ = s_ + 4; if (rp_ > (NSTEPS_) - 4) rp_ = (NSTEPS_) - 4;        \
        float4 rn_ = *(const float4*)((RP_) + rp_);                            \
        _Pragma("unroll")                                                      \
        for (int k_ = 0; k_ < 4; ++k_) {                                       \
            int tp_ = s_ + 4 + k_;                                             \
            if (tp_ > (NSTEPS_) - 1) tp_ = (NSTEPS_) - 1;                      \
            float cg_ = gq_[k_], cl_ = lq_[k_];                                \
            gq_[k_] = (GP_)[(size_t)tp_ * SDIM + i];                           \
            lq_[k_] = (LP_)[(size_t)tp_ * SDIM + i];                           \
            float r_ = (k_ == 0) ? r4_.x : (k_ == 1) ? r4_.y                   \
                      : (k_ == 2) ? r4_.z : r4_.w;                             \
            STEP1((TB_) + s_ + k_, cg_, cl_, r_, DOSTORE_)                     \
        }                                                                      \
        r4_ = rn_;                                                             \
    }                                                                          \
}

// ---------------------------------------------------------------------------
// Kernel 2: speculative-parallel scan, 1 chain/wave, 4096 waves
// (4 waves/SIMD). Pure-DPP hot path: DS pipe idle, VALU pipes (4/CU) carry
// everything, TLP from 4 wave slots fills DPP-hazard + trans bubbles.
// ---------------------------------------------------------------------------
__global__ void __launch_bounds__(64)
__attribute__((amdgpu_waves_per_eu(4, 4)))
scan_kernel(const float* __restrict__ returns,
            const float* __restrict__ gsw,
            const float* __restrict__ rsw,
            const float* __restrict__ W1,     // [64, 35]
            const float* __restrict__ b1,     // [64]
            const float* __restrict__ W2,     // [32, 64]
            const float* __restrict__ b2,     // [32]
            const float* __restrict__ X,      // fallback warm-up only
            const float* __restrict__ gb,
            const float* __restrict__ rg,
            const float* __restrict__ wsgl,   // warm windows (or null)
            const float* __restrict__ wsrl,
            float* __restrict__ out_sigma,    // [N]
            float* __restrict__ out_z,        // [N*32]  (pre-filled glN)
            float* __restrict__ out_cand,     // [N*32]  (pre-filled rlN)
            float* __restrict__ out_vfinal)   // [32]
{
    const int lane = threadIdx.x;
    const int i    = lane & 31;
    const int bid  = blockIdx.x;
    const int tstart = bid * SEG;
    const int wst    = (bid == 0) ? 0 : (tstart - WARM);

    __shared__ __align__(16) float smGB[32 * 32];   // fallback only
    __shared__ __align__(16) float smRG[32 * 32];   // fallback only

    // ---- weights, pre-scaled AND pre-permuted for the DPP rotations ----
    float gswN = -L2E * gsw[i];
    float rswN = -L2E * rsw[i];
    float w1f0 = (2.f * L2E) * W1[lane * 35 + 0];
    float w1f1 = (2.f * L2E) * W1[lane * 35 + 1];
    float w1f2 = (2.f * L2E) * W1[lane * 35 + 2];
    float w1rot[32];   // step s: rot holds rv[(lane-s)&31] -> col (lane-s)&31
#pragma unroll
    for (int s = 0; s < 32; ++s)
        w1rot[s] = (2.f * L2E) * W1[lane * 35 + 3 + ((lane - s) & 31)];
    float b1l = (2.f * L2E) * b1[lane];
    float w2rot[32];   // step s: th holds th[(lane-s)&63] -> W2[i][(lane-s)&63]
#pragma unroll
    for (int s = 0; s < 32; ++s)
        w2rot[s] = L2E * W2[i * 64 + ((lane - s) & 63)];
    float b2l = L2E * b2[i];

    PIN(gswN); PIN(rswN); PIN(b1l); PIN(b2l);
    PIN(w1f0); PIN(w1f1); PIN(w1f2);
#pragma unroll
    for (int s = 0; s < 32; ++s) { PIN(w1rot[s]); PIN(w2rot[s]); }

    // ---- initial state (wave-uniform guess; converges during warm-up) ----
    float r00 = returns[wst];
    float v = r00 * r00;

    // ---- warm-up ----
    if (wsgl) {
        const float* gw = wsgl + (size_t)bid * WARM * SDIM;
        const float* lw = wsrl + (size_t)bid * WARM * SDIM;
        PIPE1(gw, lw, returns + wst, WARM, 0, false)
    } else {
        // cold fallback (never taken when ws present): recompute gl/rl from X
        for (int k = lane; k < 1024; k += 64) {
            smGB[k] = -L2E * gb[k];
            smRG[k] = -L2E * rg[k];
        }
        __syncthreads();
        for (int t = 0; t < WARM; ++t) {
            const float* xr = X + (size_t)(wst + t) * 32;
            float a_ = 0.f, c_ = 0.f;
#pragma unroll
            for (int j = 0; j < 32; ++j) {
                float xe = xr[j];
                a_ = fmaf(xe, smGB[j * 32 + i], a_);
                c_ = fmaf(xe, smRG[j * 32 + i], c_);
            }
            float rc_ = returns[wst + t];
            STEP1(0, a_, c_, rc_, false)
        }
    }

    // block 0 starts exactly (its dummy warm-up is discarded)
    if (bid == 0) {
        float r0 = returns[0];
        v = r0 * r0;
    }

    // ---- owned segment (reads clamped to own range; overwrite in place) ----
    {
        PIPE1(out_z + (size_t)tstart * SDIM, out_cand + (size_t)tstart * SDIM,
              returns + tstart, SEG, tstart, true)
    }

    // final state (mirrored; lanes 0-31 hold all 32 states)
    if (bid == NBLK - 1 && lane < SDIM) out_vfinal[i] = v;
}

// ---------------------------------------------------------------------------
extern "C" void kernel_launch(void* const* d_in, const int* in_sizes, int n_in,
                              void* d_out, int out_size, void* d_ws, size_t ws_size,
                              hipStream_t stream)
{
    const float* X          = (const float*)d_in[0];
    const float* returns    = (const float*)d_in[1];
    const float* gate_beta  = (const float*)d_in[2];
    const float* gsw        = (const float*)d_in[3];
    const float* reset_gamma= (const float*)d_in[4];
    const float* rsw        = (const float*)d_in[5];
    const float* W1         = (const float*)d_in[6];
    const float* b1         = (const float*)d_in[7];
    const float* W2         = (const float*)d_in[8];
    const float* b2         = (const float*)d_in[9];

    float* out       = (float*)d_out;
    float* out_sigma = out;                                   // [N]
    float* out_z     = out + NT;                              // [N*S]
    float* out_cand  = out + NT + (size_t)NT * SDIM;          // [N*S]
    float* out_vfin  = out + NT + 2 * (size_t)NT * SDIM;      // [S]

    const bool use_ws = (ws_size >= WS_NEEDED);
    float* wsgl = use_ws ? (float*)d_ws : nullptr;
    float* wsrl = use_ws ? ((float*)d_ws + WSW) : nullptr;

    precompute_lin<<<(NT / 2 * SDIM) / 256, 256, 0, stream>>>(
        X, gate_beta, reset_gamma, out_z, out_cand, wsgl, wsrl);

    scan_kernel<<<NBLK, 64, 0, stream>>>(
        returns, gsw, rsw, W1, b1, W2, b2,
        X, gate_beta, reset_gamma, wsgl, wsrl,
        out_sigma, out_z, out_cand, out_vfin);
}

// Round 18
// 176.945 us; speedup vs baseline: 1.2881x; 1.0355x over previous
//
#include <hip/hip_runtime.h>

#define NT    262144
#define SDIM  32
#define NSEG  4096           // speculative segments; ONE chain per wave
#define SEG   (NT / NSEG)    // 64 steps per segment
#define WARM  32             // warm-up steps (floor-stable from 512 down to 32, r17)
#define NBLK  NSEG           // 4096 blocks -> 16 waves/CU (4/SIMD)
#define EPSV  1e-12f
#define L2E   1.4426950408889634f   // log2(e)
#define LN2   0.6931471805599453f
// warm-window copies in d_ws: NSEG windows (window 0 = dummy) of WARM x 32
#define WSW   ((size_t)NSEG * WARM * SDIM)
#define WS_NEEDED (2 * WSW * 4)     // 33.5 MB < 50.3 MB proven available

#define PIN(X_) asm volatile("" : "+v"(X_))

// ---------------------------------------------------------------------------
// Kernel 1: gl/rl precompute (pre-negated-scaled for exp2 sigmoids) + compact
// warm-window copies (unchanged from r17).
// ---------------------------------------------------------------------------
__global__ void precompute_lin(const float* __restrict__ X,
                               const float* __restrict__ gb,
                               const float* __restrict__ rg,
                               float* __restrict__ glN,
                               float* __restrict__ rlN,
                               float* __restrict__ wsgl,   // may be null
                               float* __restrict__ wsrl)
{
    int idx = blockIdx.x * blockDim.x + threadIdx.x;   // covers (NT/2)*32
    int t0 = idx >> 5, i = idx & 31;
    int t1 = t0 + NT / 2;
    const float4* xr0 = (const float4*)(X + (size_t)t0 * 32);
    const float4* xr1 = (const float4*)(X + (size_t)t1 * 32);
    float a0 = 0.f, c0 = 0.f, a1 = 0.f, c1 = 0.f;
#pragma unroll
    for (int q = 0; q < 8; ++q) {
        float4 x0 = xr0[q], x1 = xr1[q];
#pragma unroll
        for (int u = 0; u < 4; ++u) {
            int j = 4 * q + u;
            float gv = gb[j * 32 + i], rv = rg[j * 32 + i];
            float xe0 = (u == 0) ? x0.x : (u == 1) ? x0.y : (u == 2) ? x0.z : x0.w;
            float xe1 = (u == 0) ? x1.x : (u == 1) ? x1.y : (u == 2) ? x1.z : x1.w;
            a0 = fmaf(xe0, gv, a0);  c0 = fmaf(xe0, rv, c0);
            a1 = fmaf(xe1, gv, a1);  c1 = fmaf(xe1, rv, c1);
        }
    }
    a0 *= -L2E; c0 *= -L2E; a1 *= -L2E; c1 *= -L2E;
    glN[(size_t)t0 * 32 + i] = a0;  rlN[(size_t)t0 * 32 + i] = c0;
    glN[(size_t)t1 * 32 + i] = a1;  rlN[(size_t)t1 * 32 + i] = c1;
    if (wsgl) {
#pragma unroll
        for (int u = 0; u < 2; ++u) {
            int t = u ? t1 : t0;
            float a = u ? a1 : a0, c = u ? c1 : c0;
            int m  = t % SEG;
            int s1 = t / SEG + 1;
            if (m >= SEG - WARM && s1 < NSEG) {
                size_t o = ((size_t)s1 * WARM + (m - (SEG - WARM))) * SDIM + i;
                wsgl[o] = a;  wsrl[o] = c;
            }
            if (t < WARM) {                    // window 0 (dummy, seg 0)
                size_t o = (size_t)t * SDIM + i;
                wsgl[o] = a;  wsrl[o] = c;
            }
        }
    }
}

// DPP helpers (validated r9-r17)
#define DPP_ADD(S_, CTRL_)                                                     \
{   int t__ = __builtin_amdgcn_update_dpp(0, __builtin_bit_cast(int, (S_)),    \
                                          (CTRL_), 0xF, 0xF, true);            \
    (S_) += __builtin_bit_cast(float, t__); }
#define HALFSUM(S_)                                                            \
    DPP_ADD(S_, 0x111) DPP_ADD(S_, 0x112) DPP_ADD(S_, 0x114)                   \
    DPP_ADD(S_, 0x118) DPP_ADD(S_, 0x142)
// wave_ror:1 : lane l <- lane (l-1)&63; mirrored 32-vectors rotate by 1.
#define ROR1(X_)                                                               \
{   int t__ = __builtin_amdgcn_update_dpp(0, __builtin_bit_cast(int, (X_)),    \
                                          0x13C, 0xF, 0xF, true);              \
    (X_) = __builtin_bit_cast(float, t__); }

// ---------------------------------------------------------------------------
// STEP1 (hybrid, 1 chain, MIRRORED state): W1 matvec via DPP wave-rotation
// (validated r11/r17); W2 matvec via LDS th-broadcast half-dot + shfl_xor(32)
// (validated r9/r13) -- saves ~110 VALU-issue-cy/step vs pure-DPP W2, at
// d~=110 DS-cy/step on the (otherwise idle) per-CU DS pipe.
// ---------------------------------------------------------------------------
#define STEP1(TI_, GL_, RL_, RR_, DOSTORE_)                                    \
{                                                                              \
    const int ti_ = (TI_);                                                     \
    float rot_ = __builtin_amdgcn_rcpf(                                        \
        1.f + __builtin_amdgcn_exp2f(fmaf(rswN, v, (RL_)))) * v;               \
    float zg_ = fmaf(gswN, v, (GL_));                                          \
    float h_ = fmaf(w1f0, (RR_), b1l);                                         \
    h_ = fmaf(w1f1, fabsf((RR_)), h_);                                         \
    h_ = fmaf(w1f2, (RR_) * (RR_), h_);                                        \
    _Pragma("unroll")                                                          \
    for (int s_ = 0; s_ < 32; ++s_) {                                          \
        h_ = fmaf(w1rot[s_], rot_, h_);                                        \
        if (s_ != 31) { ROR1(rot_) }                                           \
    }                                                                          \
    float th_ = fmaf(-2.f, __builtin_amdgcn_rcpf(                              \
                   __builtin_amdgcn_exp2f(h_) + 1.f), 1.f);                    \
    smB[lane] = th_;                                                           \
    __builtin_amdgcn_wave_barrier();                                           \
    float z_ = __builtin_amdgcn_rcpf(1.f + __builtin_amdgcn_exp2f(zg_));       \
    float q0_ = 0.f, q1_ = 0.f, q2_ = 0.f, q3_ = 0.f;                          \
    {                                                                          \
        const float4* pa_ = (const float4*)(smB + (half << 5));                \
        _Pragma("unroll")                                                      \
        for (int q_ = 0; q_ < 8; ++q_) {                                       \
            float4 ca_ = pa_[q_];                                              \
            q0_ = fmaf(w2r[4 * q_ + 0], ca_.x, q0_);                           \
            q1_ = fmaf(w2r[4 * q_ + 1], ca_.y, q1_);                           \
            q2_ = fmaf(w2r[4 * q_ + 2], ca_.z, q2_);                           \
            q3_ = fmaf(w2r[4 * q_ + 3], ca_.w, q3_);                           \
        }                                                                      \
    }                                                                          \
    __builtin_amdgcn_wave_barrier();                                           \
    float p_ = (q0_ + q1_) + (q2_ + q3_);                                      \
    p_ += __shfl_xor(p_, 32);                                                  \
    float raw_ = p_ + b2l;                                                     \
    float cand_ = LN2 * (fmaxf(raw_, 0.f) + __builtin_amdgcn_logf(             \
                  1.f + __builtin_amdgcn_exp2f(-fabsf(raw_))));                \
    float vn_ = fmaxf(fmaf(z_, cand_ - v, v), EPSV);                           \
    if (DOSTORE_) {                                                            \
        out_z  [(size_t)ti_ * SDIM + i] = z_;   /* both halves: same value */  \
        out_cand[(size_t)ti_ * SDIM + i] = cand_;                              \
        float s_ = vn_;                                                        \
        HALFSUM(s_)                                                            \
        if (lane == 63) out_sigma[ti_] = s_ * (1.f / 32.f);                    \
    }                                                                          \
    v = vn_;                                                                   \
}

// 1-deep double-buffer run (TLP from 4 waves/SIMD hides the load latency;
// the 4-deep queue of r10-r17 was pure issue overhead at this occupancy).
#define PIPE1(GP_, LP_, RP_, NSTEPS_, TB_, DOSTORE_)                           \
{                                                                              \
    float gn_ = (GP_)[i];                                                      \
    float ln_ = (LP_)[i];                                                      \
    float4 r4_ = *(const float4*)(RP_);                                        \
    for (int s_ = 0; s_ < (NSTEPS_); s_ += 4) {                                \
        int rp_ = s_ + 4; if (rp_ > (NSTEPS_) - 4) rp_ = (NSTEPS_) - 4;        \
        float4 rn_ = *(const float4*)((RP_) + rp_);                            \
        _Pragma("unroll")                                                      \
        for (int k_ = 0; k_ < 4; ++k_) {                                       \
            float g_ = gn_, l_ = ln_;                                          \
            int tp_ = s_ + k_ + 1;                                             \
            if (tp_ > (NSTEPS_) - 1) tp_ = (NSTEPS_) - 1;                      \
            gn_ = (GP_)[(size_t)tp_ * SDIM + i];                               \
            ln_ = (LP_)[(size_t)tp_ * SDIM + i];                               \
            float r_ = (k_ == 0) ? r4_.x : (k_ == 1) ? r4_.y                   \
                      : (k_ == 2) ? r4_.z : r4_.w;                             \
            STEP1((TB_) + s_ + k_, g_, l_, r_, DOSTORE_)                       \
        }                                                                      \
        r4_ = rn_;                                                             \
    }                                                                          \
}

// ---------------------------------------------------------------------------
// Kernel 2: speculative-parallel scan, 1 chain/wave, 4096 waves (4/SIMD).
// Hybrid step: W1 on VALU/DPP, W2 on the otherwise-idle DS pipe. LDS usage
// is 512 B/block (fallback LDS removed) so occupancy is not LDS-capped.
// ---------------------------------------------------------------------------
__global__ void __launch_bounds__(64)
__attribute__((amdgpu_waves_per_eu(4, 4)))
scan_kernel(const float* __restrict__ returns,
            const float* __restrict__ gsw,
            const float* __restrict__ rsw,
            const float* __restrict__ W1,     // [64, 35]
            const float* __restrict__ b1,     // [64]
            const float* __restrict__ W2,     // [32, 64]
            const float* __restrict__ b2,     // [32]
            const float* __restrict__ X,      // fallback warm-up only
            const float* __restrict__ gb,
            const float* __restrict__ rg,
            const float* __restrict__ wsgl,   // warm windows (or null)
            const float* __restrict__ wsrl,
            float* __restrict__ out_sigma,    // [N]
            float* __restrict__ out_z,        // [N*32]  (pre-filled glN)
            float* __restrict__ out_cand,     // [N*32]  (pre-filled rlN)
            float* __restrict__ out_vfinal)   // [32]
{
    const int lane = threadIdx.x;
    const int i    = lane & 31;
    const int half = lane >> 5;
    const int bid  = blockIdx.x;
    const int tstart = bid * SEG;
    const int wst    = (bid == 0) ? 0 : (tstart - WARM);

    __shared__ __align__(16) float smB[64];   // th broadcast (1 chain)

    // ---- weights, pre-scaled; W1 pre-permuted for the DPP rotation ----
    float gswN = -L2E * gsw[i];
    float rswN = -L2E * rsw[i];
    float w1f0 = (2.f * L2E) * W1[lane * 35 + 0];
    float w1f1 = (2.f * L2E) * W1[lane * 35 + 1];
    float w1f2 = (2.f * L2E) * W1[lane * 35 + 2];
    float w1rot[32];   // step s: rot holds rv[(lane-s)&31] -> col (lane-s)&31
#pragma unroll
    for (int s = 0; s < 32; ++s)
        w1rot[s] = (2.f * L2E) * W1[lane * 35 + 3 + ((lane - s) & 31)];
    float b1l = (2.f * L2E) * b1[lane];
    float w2r[32];     // half-dot: cols (half*32)..+31 of row i
#pragma unroll
    for (int j = 0; j < 32; ++j) w2r[j] = L2E * W2[i * 64 + (half << 5) + j];
    float b2l = L2E * b2[i];

    PIN(gswN); PIN(rswN); PIN(b1l); PIN(b2l);
    PIN(w1f0); PIN(w1f1); PIN(w1f2);
#pragma unroll
    for (int s = 0; s < 32; ++s) { PIN(w1rot[s]); PIN(w2r[s]); }

    // ---- initial state (wave-uniform guess; converges during warm-up) ----
    float r00 = returns[wst];
    float v = r00 * r00;

    // ---- warm-up ----
    if (wsgl) {
        const float* gw = wsgl + (size_t)bid * WARM * SDIM;
        const float* lw = wsrl + (size_t)bid * WARM * SDIM;
        PIPE1(gw, lw, returns + wst, WARM, 0, false)
    } else {
        // cold fallback (never taken when ws present): recompute gl/rl from
        // X and global betas (L2-resident); no LDS staging.
        for (int t = 0; t < WARM; ++t) {
            const float* xr = X + (size_t)(wst + t) * 32;
            float a_ = 0.f, c_ = 0.f;
#pragma unroll
            for (int j = 0; j < 32; ++j) {
                float xe = xr[j];
                a_ = fmaf(xe, gb[j * 32 + i], a_);
                c_ = fmaf(xe, rg[j * 32 + i], c_);
            }
            a_ *= -L2E;  c_ *= -L2E;
            float rc_ = returns[wst + t];
            STEP1(0, a_, c_, rc_, false)
        }
    }

    // block 0 starts exactly (its dummy warm-up is discarded)
    if (bid == 0) {
        float r0 = returns[0];
        v = r0 * r0;
    }

    // ---- owned segment (reads clamped to own range; overwrite in place) ----
    {
        PIPE1(out_z + (size_t)tstart * SDIM, out_cand + (size_t)tstart * SDIM,
              returns + tstart, SEG, tstart, true)
    }

    // final state (mirrored; lanes 0-31 hold all 32 states)
    if (bid == NBLK - 1 && lane < SDIM) out_vfinal[i] = v;
}

// ---------------------------------------------------------------------------
extern "C" void kernel_launch(void* const* d_in, const int* in_sizes, int n_in,
                              void* d_out, int out_size, void* d_ws, size_t ws_size,
                              hipStream_t stream)
{
    const float* X          = (const float*)d_in[0];
    const float* returns    = (const float*)d_in[1];
    const float* gate_beta  = (const float*)d_in[2];
    const float* gsw        = (const float*)d_in[3];
    const float* reset_gamma= (const float*)d_in[4];
    const float* rsw        = (const float*)d_in[5];
    const float* W1         = (const float*)d_in[6];
    const float* b1         = (const float*)d_in[7];
    const float* W2         = (const float*)d_in[8];
    const float* b2         = (const float*)d_in[9];

    float* out       = (float*)d_out;
    float* out_sigma = out;                                   // [N]
    float* out_z     = out + NT;                              // [N*S]
    float* out_cand  = out + NT + (size_t)NT * SDIM;          // [N*S]
    float* out_vfin  = out + NT + 2 * (size_t)NT * SDIM;      // [S]

    const bool use_ws = (ws_size >= WS_NEEDED);
    float* wsgl = use_ws ? (float*)d_ws : nullptr;
    float* wsrl = use_ws ? ((float*)d_ws + WSW) : nullptr;

    precompute_lin<<<(NT / 2 * SDIM) / 256, 256, 0, stream>>>(
        X, gate_beta, reset_gamma, out_z, out_cand, wsgl, wsrl);

    scan_kernel<<<NBLK, 64, 0, stream>>>(
        returns, gsw, rsw, W1, b1, W2, b2,
        X, gate_beta, reset_gamma, wsgl, wsrl,
        out_sigma, out_z, out_cand, out_vfin);
}

// Round 19
// 176.822 us; speedup vs baseline: 1.2890x; 1.0007x over previous
//
#include <hip/hip_runtime.h>

#define NT    262144
#define SDIM  32
#define NSEG  4096           // speculative segments; ONE chain per wave
#define SEG   (NT / NSEG)    // 64 steps per segment
#define WARM  32             // warm-up steps (floor-stable from 512 down to 32, r17)
#define NBLK  NSEG           // 4096 blocks -> 16 waves/CU (4/SIMD)
#define EPSV  1e-12f
#define L2E   1.4426950408889634f   // log2(e)
#define LN2   0.6931471805599453f
// warm-window copies in d_ws: NSEG windows (window 0 = dummy) of WARM x 32
#define WSW   ((size_t)NSEG * WARM * SDIM)
#define WS_NEEDED (2 * WSW * 4)     // 33.5 MB < 50.3 MB proven available

#define PIN(X_) asm volatile("" : "+v"(X_))

// ---------------------------------------------------------------------------
// Kernel 1: gl/rl precompute (pre-negated-scaled for exp2 sigmoids) + compact
// warm-window copies (unchanged from r17/r18).
// ---------------------------------------------------------------------------
__global__ void precompute_lin(const float* __restrict__ X,
                               const float* __restrict__ gb,
                               const float* __restrict__ rg,
                               float* __restrict__ glN,
                               float* __restrict__ rlN,
                               float* __restrict__ wsgl,   // may be null
                               float* __restrict__ wsrl)
{
    int idx = blockIdx.x * blockDim.x + threadIdx.x;   // covers (NT/2)*32
    int t0 = idx >> 5, i = idx & 31;
    int t1 = t0 + NT / 2;
    const float4* xr0 = (const float4*)(X + (size_t)t0 * 32);
    const float4* xr1 = (const float4*)(X + (size_t)t1 * 32);
    float a0 = 0.f, c0 = 0.f, a1 = 0.f, c1 = 0.f;
#pragma unroll
    for (int q = 0; q < 8; ++q) {
        float4 x0 = xr0[q], x1 = xr1[q];
#pragma unroll
        for (int u = 0; u < 4; ++u) {
            int j = 4 * q + u;
            float gv = gb[j * 32 + i], rv = rg[j * 32 + i];
            float xe0 = (u == 0) ? x0.x : (u == 1) ? x0.y : (u == 2) ? x0.z : x0.w;
            float xe1 = (u == 0) ? x1.x : (u == 1) ? x1.y : (u == 2) ? x1.z : x1.w;
            a0 = fmaf(xe0, gv, a0);  c0 = fmaf(xe0, rv, c0);
            a1 = fmaf(xe1, gv, a1);  c1 = fmaf(xe1, rv, c1);
        }
    }
    a0 *= -L2E; c0 *= -L2E; a1 *= -L2E; c1 *= -L2E;
    glN[(size_t)t0 * 32 + i] = a0;  rlN[(size_t)t0 * 32 + i] = c0;
    glN[(size_t)t1 * 32 + i] = a1;  rlN[(size_t)t1 * 32 + i] = c1;
    if (wsgl) {
#pragma unroll
        for (int u = 0; u < 2; ++u) {
            int t = u ? t1 : t0;
            float a = u ? a1 : a0, c = u ? c1 : c0;
            int m  = t % SEG;
            int s1 = t / SEG + 1;
            if (m >= SEG - WARM && s1 < NSEG) {
                size_t o = ((size_t)s1 * WARM + (m - (SEG - WARM))) * SDIM + i;
                wsgl[o] = a;  wsrl[o] = c;
            }
            if (t < WARM) {                    // window 0 (dummy, seg 0)
                size_t o = (size_t)t * SDIM + i;
                wsgl[o] = a;  wsrl[o] = c;
            }
        }
    }
}

// DPP helpers (validated r9-r18)
#define DPP_ADD(S_, CTRL_)                                                     \
{   int t__ = __builtin_amdgcn_update_dpp(0, __builtin_bit_cast(int, (S_)),    \
                                          (CTRL_), 0xF, 0xF, true);            \
    (S_) += __builtin_bit_cast(float, t__); }
#define HALFSUM(S_)                                                            \
    DPP_ADD(S_, 0x111) DPP_ADD(S_, 0x112) DPP_ADD(S_, 0x114)                   \
    DPP_ADD(S_, 0x118) DPP_ADD(S_, 0x142)
// wave_ror:1 : lane l <- lane (l-1)&63; mirrored 32-vectors rotate by 1.
#define ROR1(X_)                                                               \
{   int t__ = __builtin_amdgcn_update_dpp(0, __builtin_bit_cast(int, (X_)),    \
                                          0x13C, 0xF, 0xF, true);              \
    (X_) = __builtin_bit_cast(float, t__); }

// ---------------------------------------------------------------------------
// STEP1 (hybrid, 1 chain, MIRRORED state): W1 matvec via DPP wave-rotation
// (validated r11/r17); W2 matvec via LDS th-broadcast half-dot + shfl_xor(32)
// (validated r9/r13/r18).
// ---------------------------------------------------------------------------
#define STEP1(TI_, GL_, RL_, RR_, DOSTORE_)                                    \
{                                                                              \
    const int ti_ = (TI_);                                                     \
    float rot_ = __builtin_amdgcn_rcpf(                                        \
        1.f + __builtin_amdgcn_exp2f(fmaf(rswN, v, (RL_)))) * v;               \
    float zg_ = fmaf(gswN, v, (GL_));                                          \
    float h_ = fmaf(w1f0, (RR_), b1l);                                         \
    h_ = fmaf(w1f1, fabsf((RR_)), h_);                                         \
    h_ = fmaf(w1f2, (RR_) * (RR_), h_);                                        \
    _Pragma("unroll")                                                          \
    for (int s_ = 0; s_ < 32; ++s_) {                                          \
        h_ = fmaf(w1rot[s_], rot_, h_);                                        \
        if (s_ != 31) { ROR1(rot_) }                                           \
    }                                                                          \
    float th_ = fmaf(-2.f, __builtin_amdgcn_rcpf(                              \
                   __builtin_amdgcn_exp2f(h_) + 1.f), 1.f);                    \
    smB[lane] = th_;                                                           \
    __builtin_amdgcn_wave_barrier();                                           \
    float z_ = __builtin_amdgcn_rcpf(1.f + __builtin_amdgcn_exp2f(zg_));       \
    float q0_ = 0.f, q1_ = 0.f, q2_ = 0.f, q3_ = 0.f;                          \
    {                                                                          \
        const float4* pa_ = (const float4*)(smB + (half << 5));                \
        _Pragma("unroll")                                                      \
        for (int q_ = 0; q_ < 8; ++q_) {                                       \
            float4 ca_ = pa_[q_];                                              \
            q0_ = fmaf(w2r[4 * q_ + 0], ca_.x, q0_);                           \
            q1_ = fmaf(w2r[4 * q_ + 1], ca_.y, q1_);                           \
            q2_ = fmaf(w2r[4 * q_ + 2], ca_.z, q2_);                           \
            q3_ = fmaf(w2r[4 * q_ + 3], ca_.w, q3_);                           \
        }                                                                      \
    }                                                                          \
    __builtin_amdgcn_wave_barrier();                                           \
    float p_ = (q0_ + q1_) + (q2_ + q3_);                                      \
    p_ += __shfl_xor(p_, 32);                                                  \
    float raw_ = p_ + b2l;                                                     \
    float cand_ = LN2 * (fmaxf(raw_, 0.f) + __builtin_amdgcn_logf(             \
                  1.f + __builtin_amdgcn_exp2f(-fabsf(raw_))));                \
    float vn_ = fmaxf(fmaf(z_, cand_ - v, v), EPSV);                           \
    if (DOSTORE_) {                                                            \
        out_z  [(size_t)ti_ * SDIM + i] = z_;   /* both halves: same value */  \
        out_cand[(size_t)ti_ * SDIM + i] = cand_;                              \
        float s_ = vn_;                                                        \
        HALFSUM(s_)                                                            \
        if (lane == 63) out_sigma[ti_] = s_ * (1.f / 32.f);                    \
    }                                                                          \
    v = vn_;                                                                   \
}

// 1-deep double-buffer run (TLP from 4 waves/SIMD hides the load latency).
#define PIPE1(GP_, LP_, RP_, NSTEPS_, TB_, DOSTORE_)                           \
{                                                                              \
    float gn_ = (GP_)[i];                                                      \
    float ln_ = (LP_)[i];                                                      \
    float4 r4_ = *(const float4*)(RP_);                                        \
    for (int s_ = 0; s_ < (NSTEPS_); s_ += 4) {                                \
        int rp_ = s_ + 4; if (rp_ > (NSTEPS_) - 4) rp_ = (NSTEPS_) - 4;        \
        float4 rn_ = *(const float4*)((RP_) + rp_);                            \
        _Pragma("unroll")                                                      \
        for (int k_ = 0; k_ < 4; ++k_) {                                       \
            float g_ = gn_, l_ = ln_;                                          \
            int tp_ = s_ + k_ + 1;                                             \
            if (tp_ > (NSTEPS_) - 1) tp_ = (NSTEPS_) - 1;                      \
            gn_ = (GP_)[(size_t)tp_ * SDIM + i];                               \
            ln_ = (LP_)[(size_t)tp_ * SDIM + i];                               \
            float r_ = (k_ == 0) ? r4_.x : (k_ == 1) ? r4_.y                   \
                      : (k_ == 2) ? r4_.z : r4_.w;                             \
            STEP1((TB_) + s_ + k_, g_, l_, r_, DOSTORE_)                       \
        }                                                                      \
        r4_ = rn_;                                                             \
    }                                                                          \
}

// ---------------------------------------------------------------------------
// Kernel 2: speculative-parallel scan, 1 chain/wave, 4096 waves (4/SIMD).
// amdgpu_num_vgpr(112): direct allocation budget -- r17/r18 showed the
// allocator targeting the DEFAULT 8-wave 64-reg budget despite
// waves_per_eu(4,4), evicting ~27 of the 71 pinned weight regs per step
// (AGPR/scratch shuffle = the unexplained ~280 issue-cy/step). 112 >= ~91
// live values, floor(512/112)=4 waves/SIMD unchanged.
// ---------------------------------------------------------------------------
__global__ void __launch_bounds__(64)
__attribute__((amdgpu_waves_per_eu(4, 4)))
__attribute__((amdgpu_num_vgpr(112)))
scan_kernel(const float* __restrict__ returns,
            const float* __restrict__ gsw,
            const float* __restrict__ rsw,
            const float* __restrict__ W1,     // [64, 35]
            const float* __restrict__ b1,     // [64]
            const float* __restrict__ W2,     // [32, 64]
            const float* __restrict__ b2,     // [32]
            const float* __restrict__ X,      // fallback warm-up only
            const float* __restrict__ gb,
            const float* __restrict__ rg,
            const float* __restrict__ wsgl,   // warm windows (or null)
            const float* __restrict__ wsrl,
            float* __restrict__ out_sigma,    // [N]
            float* __restrict__ out_z,        // [N*32]  (pre-filled glN)
            float* __restrict__ out_cand,     // [N*32]  (pre-filled rlN)
            float* __restrict__ out_vfinal)   // [32]
{
    const int lane = threadIdx.x;
    const int i    = lane & 31;
    const int half = lane >> 5;
    const int bid  = blockIdx.x;
    const int tstart = bid * SEG;
    const int wst    = (bid == 0) ? 0 : (tstart - WARM);

    __shared__ __align__(16) float smB[64];   // th broadcast (1 chain)

    // ---- weights, pre-scaled; W1 pre-permuted for the DPP rotation ----
    float gswN = -L2E * gsw[i];
    float rswN = -L2E * rsw[i];
    float w1f0 = (2.f * L2E) * W1[lane * 35 + 0];
    float w1f1 = (2.f * L2E) * W1[lane * 35 + 1];
    float w1f2 = (2.f * L2E) * W1[lane * 35 + 2];
    float w1rot[32];   // step s: rot holds rv[(lane-s)&31] -> col (lane-s)&31
#pragma unroll
    for (int s = 0; s < 32; ++s)
        w1rot[s] = (2.f * L2E) * W1[lane * 35 + 3 + ((lane - s) & 31)];
    float b1l = (2.f * L2E) * b1[lane];
    float w2r[32];     // half-dot: cols (half*32)..+31 of row i
#pragma unroll
    for (int j = 0; j < 32; ++j) w2r[j] = L2E * W2[i * 64 + (half << 5) + j];
    float b2l = L2E * b2[i];

    PIN(gswN); PIN(rswN); PIN(b1l); PIN(b2l);
    PIN(w1f0); PIN(w1f1); PIN(w1f2);
#pragma unroll
    for (int s = 0; s < 32; ++s) { PIN(w1rot[s]); PIN(w2r[s]); }

    // ---- initial state (wave-uniform guess; converges during warm-up) ----
    float r00 = returns[wst];
    float v = r00 * r00;

    // ---- warm-up ----
    if (wsgl) {
        const float* gw = wsgl + (size_t)bid * WARM * SDIM;
        const float* lw = wsrl + (size_t)bid * WARM * SDIM;
        PIPE1(gw, lw, returns + wst, WARM, 0, false)
    } else {
        // cold fallback (never taken when ws present): recompute gl/rl from
        // X and global betas (L2-resident); no LDS staging.
        for (int t = 0; t < WARM; ++t) {
            const float* xr = X + (size_t)(wst + t) * 32;
            float a_ = 0.f, c_ = 0.f;
#pragma unroll
            for (int j = 0; j < 32; ++j) {
                float xe = xr[j];
                a_ = fmaf(xe, gb[j * 32 + i], a_);
                c_ = fmaf(xe, rg[j * 32 + i], c_);
            }
            a_ *= -L2E;  c_ *= -L2E;
            float rc_ = returns[wst + t];
            STEP1(0, a_, c_, rc_, false)
        }
    }

    // block 0 starts exactly (its dummy warm-up is discarded)
    if (bid == 0) {
        float r0 = returns[0];
        v = r0 * r0;
    }

    // ---- owned segment (reads clamped to own range; overwrite in place) ----
    {
        PIPE1(out_z + (size_t)tstart * SDIM, out_cand + (size_t)tstart * SDIM,
              returns + tstart, SEG, tstart, true)
    }

    // final state (mirrored; lanes 0-31 hold all 32 states)
    if (bid == NBLK - 1 && lane < SDIM) out_vfinal[i] = v;
}

// ---------------------------------------------------------------------------
extern "C" void kernel_launch(void* const* d_in, const int* in_sizes, int n_in,
                              void* d_out, int out_size, void* d_ws, size_t ws_size,
                              hipStream_t stream)
{
    const float* X          = (const float*)d_in[0];
    const float* returns    = (const float*)d_in[1];
    const float* gate_beta  = (const float*)d_in[2];
    const float* gsw        = (const float*)d_in[3];
    const float* reset_gamma= (const float*)d_in[4];
    const float* rsw        = (const float*)d_in[5];
    const float* W1         = (const float*)d_in[6];
    const float* b1         = (const float*)d_in[7];
    const float* W2         = (const float*)d_in[8];
    const float* b2         = (const float*)d_in[9];

    float* out       = (float*)d_out;
    float* out_sigma = out;                                   // [N]
    float* out_z     = out + NT;                              // [N*S]
    float* out_cand  = out + NT + (size_t)NT * SDIM;          // [N*S]
    float* out_vfin  = out + NT + 2 * (size_t)NT * SDIM;      // [S]

    const bool use_ws = (ws_size >= WS_NEEDED);
    float* wsgl = use_ws ? (float*)d_ws : nullptr;
    float* wsrl = use_ws ? ((float*)d_ws + WSW) : nullptr;

    precompute_lin<<<(NT / 2 * SDIM) / 256, 256, 0, stream>>>(
        X, gate_beta, reset_gamma, out_z, out_cand, wsgl, wsrl);

    scan_kernel<<<NBLK, 64, 0, stream>>>(
        returns, gsw, rsw, W1, b1, W2, b2,
        X, gate_beta, reset_gamma, wsgl, wsrl,
        out_sigma, out_z, out_cand, out_vfin);
}

// Round 20
// 160.638 us; speedup vs baseline: 1.4189x; 1.1008x over previous
//
#include <hip/hip_runtime.h>

#define NT    262144
#define SDIM  32
#define NSEG  4096           // speculative segments; ONE chain per wave
#define SEG   (NT / NSEG)    // 64 steps per segment
#define WARM  16             // warm-up steps (floor-stable 512->32; lambda^16 ~ 3e-4)
#define NBLK  NSEG           // 4096 blocks -> 16 waves/CU (4/SIMD)
#define EPSV  1e-12f
#define L2E   1.4426950408889634f   // log2(e)
#define LN2   0.6931471805599453f
// warm-window copies in d_ws: NSEG windows (window 0 = dummy) of WARM x 32
#define WSW   ((size_t)NSEG * WARM * SDIM)
#define WS_NEEDED (2 * WSW * 4)     // 16.8 MB << 50.3 MB proven available

#define PIN(X_) asm volatile("" : "+v"(X_))

// ---------------------------------------------------------------------------
// Kernel 1: gl/rl precompute (pre-negated-scaled for exp2 sigmoids) + compact
// warm-window copies.
// ---------------------------------------------------------------------------
__global__ void precompute_lin(const float* __restrict__ X,
                               const float* __restrict__ gb,
                               const float* __restrict__ rg,
                               float* __restrict__ glN,
                               float* __restrict__ rlN,
                               float* __restrict__ wsgl,   // may be null
                               float* __restrict__ wsrl)
{
    int idx = blockIdx.x * blockDim.x + threadIdx.x;   // covers (NT/2)*32
    int t0 = idx >> 5, i = idx & 31;
    int t1 = t0 + NT / 2;
    const float4* xr0 = (const float4*)(X + (size_t)t0 * 32);
    const float4* xr1 = (const float4*)(X + (size_t)t1 * 32);
    float a0 = 0.f, c0 = 0.f, a1 = 0.f, c1 = 0.f;
#pragma unroll
    for (int q = 0; q < 8; ++q) {
        float4 x0 = xr0[q], x1 = xr1[q];
#pragma unroll
        for (int u = 0; u < 4; ++u) {
            int j = 4 * q + u;
            float gv = gb[j * 32 + i], rv = rg[j * 32 + i];
            float xe0 = (u == 0) ? x0.x : (u == 1) ? x0.y : (u == 2) ? x0.z : x0.w;
            float xe1 = (u == 0) ? x1.x : (u == 1) ? x1.y : (u == 2) ? x1.z : x1.w;
            a0 = fmaf(xe0, gv, a0);  c0 = fmaf(xe0, rv, c0);
            a1 = fmaf(xe1, gv, a1);  c1 = fmaf(xe1, rv, c1);
        }
    }
    a0 *= -L2E; c0 *= -L2E; a1 *= -L2E; c1 *= -L2E;
    glN[(size_t)t0 * 32 + i] = a0;  rlN[(size_t)t0 * 32 + i] = c0;
    glN[(size_t)t1 * 32 + i] = a1;  rlN[(size_t)t1 * 32 + i] = c1;
    if (wsgl) {
#pragma unroll
        for (int u = 0; u < 2; ++u) {
            int t = u ? t1 : t0;
            float a = u ? a1 : a0, c = u ? c1 : c0;
            int m  = t % SEG;
            int s1 = t / SEG + 1;
            if (m >= SEG - WARM && s1 < NSEG) {
                size_t o = ((size_t)s1 * WARM + (m - (SEG - WARM))) * SDIM + i;
                wsgl[o] = a;  wsrl[o] = c;
            }
            if (t < WARM) {                    // window 0 (dummy, seg 0)
                size_t o = (size_t)t * SDIM + i;
                wsgl[o] = a;  wsrl[o] = c;
            }
        }
    }
}

// DPP helpers (validated r9-r19)
#define DPP_ADD(S_, CTRL_)                                                     \
{   int t__ = __builtin_amdgcn_update_dpp(0, __builtin_bit_cast(int, (S_)),    \
                                          (CTRL_), 0xF, 0xF, true);            \
    (S_) += __builtin_bit_cast(float, t__); }
#define HALFSUM(S_)                                                            \
    DPP_ADD(S_, 0x111) DPP_ADD(S_, 0x112) DPP_ADD(S_, 0x114)                   \
    DPP_ADD(S_, 0x118) DPP_ADD(S_, 0x142)
// wave_ror:1 : lane l <- lane (l-1)&63; mirrored 32-vectors rotate by 1.
#define ROR1(X_)                                                               \
{   int t__ = __builtin_amdgcn_update_dpp(0, __builtin_bit_cast(int, (X_)),    \
                                          0x13C, 0xF, 0xF, true);              \
    (X_) = __builtin_bit_cast(float, t__); }

// ---------------------------------------------------------------------------
// STEP1 (hybrid, 1 chain, MIRRORED state): W1 matvec via DPP wave-rotation;
// W2 matvec via LDS th-broadcast half-dot + shfl_xor(32). (validated r18)
// ---------------------------------------------------------------------------
#define STEP1(TI_, GL_, RL_, RR_, DOSTORE_)                                    \
{                                                                              \
    const int ti_ = (TI_);                                                     \
    float rot_ = __builtin_amdgcn_rcpf(                                        \
        1.f + __builtin_amdgcn_exp2f(fmaf(rswN, v, (RL_)))) * v;               \
    float zg_ = fmaf(gswN, v, (GL_));                                          \
    float h_ = fmaf(w1f0, (RR_), b1l);                                         \
    h_ = fmaf(w1f1, fabsf((RR_)), h_);                                         \
    h_ = fmaf(w1f2, (RR_) * (RR_), h_);                                        \
    _Pragma("unroll")                                                          \
    for (int s_ = 0; s_ < 32; ++s_) {                                          \
        h_ = fmaf(w1rot[s_], rot_, h_);                                        \
        if (s_ != 31) { ROR1(rot_) }                                           \
    }                                                                          \
    float th_ = fmaf(-2.f, __builtin_amdgcn_rcpf(                              \
                   __builtin_amdgcn_exp2f(h_) + 1.f), 1.f);                    \
    smB[lane] = th_;                                                           \
    __builtin_amdgcn_wave_barrier();                                           \
    float z_ = __builtin_amdgcn_rcpf(1.f + __builtin_amdgcn_exp2f(zg_));       \
    float q0_ = 0.f, q1_ = 0.f, q2_ = 0.f, q3_ = 0.f;                          \
    {                                                                          \
        const float4* pa_ = (const float4*)(smB + (half << 5));                \
        _Pragma("unroll")                                                      \
        for (int q_ = 0; q_ < 8; ++q_) {                                       \
            float4 ca_ = pa_[q_];                                              \
            q0_ = fmaf(w2r[4 * q_ + 0], ca_.x, q0_);                           \
            q1_ = fmaf(w2r[4 * q_ + 1], ca_.y, q1_);                           \
            q2_ = fmaf(w2r[4 * q_ + 2], ca_.z, q2_);                           \
            q3_ = fmaf(w2r[4 * q_ + 3], ca_.w, q3_);                           \
        }                                                                      \
    }                                                                          \
    __builtin_amdgcn_wave_barrier();                                           \
    float p_ = (q0_ + q1_) + (q2_ + q3_);                                      \
    p_ += __shfl_xor(p_, 32);                                                  \
    float raw_ = p_ + b2l;                                                     \
    float cand_ = LN2 * (fmaxf(raw_, 0.f) + __builtin_amdgcn_logf(             \
                  1.f + __builtin_amdgcn_exp2f(-fabsf(raw_))));                \
    float vn_ = fmaxf(fmaf(z_, cand_ - v, v), EPSV);                           \
    if (DOSTORE_) {                                                            \
        out_z  [(size_t)ti_ * SDIM + i] = z_;   /* both halves: same value */  \
        out_cand[(size_t)ti_ * SDIM + i] = cand_;                              \
        float s_ = vn_;                                                        \
        HALFSUM(s_)                                                            \
        if (lane == 63) out_sigma[ti_] = s_ * (1.f / 32.f);                    \
    }                                                                          \
    v = vn_;                                                                   \
}

// 1-deep double-buffer run; CLAMP-FREE main loop (pointer-bump addressing),
// peeled 4-step tail handles the lookahead boundary. Requires NSTEPS_ % 4 == 0
// and NSTEPS_ >= 4.
#define PIPE1(GP_, LP_, RP_, NSTEPS_, TB_, DOSTORE_)                           \
{                                                                              \
    const float* gp_ = (GP_) + i;                                              \
    const float* lp_ = (LP_) + i;                                              \
    float gn_ = *gp_;  gp_ += SDIM;                                            \
    float ln_ = *lp_;  lp_ += SDIM;                                            \
    float4 r4_ = *(const float4*)(RP_);                                        \
    int s_ = 0;                                                                \
    for (; s_ + 8 <= (NSTEPS_); s_ += 4) {                                     \
        float4 rn_ = *(const float4*)((RP_) + s_ + 4);                         \
        _Pragma("unroll")                                                      \
        for (int k_ = 0; k_ < 4; ++k_) {                                       \
            float g_ = gn_, l_ = ln_;                                          \
            gn_ = *gp_;  gp_ += SDIM;                                          \
            ln_ = *lp_;  lp_ += SDIM;                                          \
            float r_ = (k_ == 0) ? r4_.x : (k_ == 1) ? r4_.y                   \
                      : (k_ == 2) ? r4_.z : r4_.w;                             \
            STEP1((TB_) + s_ + k_, g_, l_, r_, DOSTORE_)                       \
        }                                                                      \
        r4_ = rn_;                                                             \
    }                                                                          \
    _Pragma("unroll")                                                          \
    for (int k_ = 0; k_ < 4; ++k_) {      /* tail: steps s_..s_+3 */           \
        float g_ = gn_, l_ = ln_;                                              \
        if (k_ < 3) {                                                          \
            gn_ = *gp_;  gp_ += SDIM;                                          \
            ln_ = *lp_;  lp_ += SDIM;                                          \
        }                                                                      \
        float r_ = (k_ == 0) ? r4_.x : (k_ == 1) ? r4_.y                       \
                  : (k_ == 2) ? r4_.z : r4_.w;                                 \
        STEP1((TB_) + s_ + k_, g_, l_, r_, DOSTORE_)                           \
    }                                                                          \
}

// ---------------------------------------------------------------------------
// Kernel 2: speculative-parallel scan, 1 chain/wave, 4096 waves (4/SIMD).
// Hybrid step (W1 DPP / W2 LDS). VGPR=64 + weights in AGPR (unified file,
// VALU reads AGPR operands directly) -- r18/r19 showed this is NOT a spill
// pathology; the remaining cost is issue + C, attacked here.
// ---------------------------------------------------------------------------
__global__ void __launch_bounds__(64)
__attribute__((amdgpu_waves_per_eu(4, 4)))
scan_kernel(const float* __restrict__ returns,
            const float* __restrict__ gsw,
            const float* __restrict__ rsw,
            const float* __restrict__ W1,     // [64, 35]
            const float* __restrict__ b1,     // [64]
            const float* __restrict__ W2,     // [32, 64]
            const float* __restrict__ b2,     // [32]
            const float* __restrict__ X,      // fallback warm-up only
            const float* __restrict__ gb,
            const float* __restrict__ rg,
            const float* __restrict__ wsgl,   // warm windows (or null)
            const float* __restrict__ wsrl,
            float* __restrict__ out_sigma,    // [N]
            float* __restrict__ out_z,        // [N*32]  (pre-filled glN)
            float* __restrict__ out_cand,     // [N*32]  (pre-filled rlN)
            float* __restrict__ out_vfinal)   // [32]
{
    const int lane = threadIdx.x;
    const int i    = lane & 31;
    const int half = lane >> 5;
    const int bid  = blockIdx.x;
    const int tstart = bid * SEG;
    const int wst    = (bid == 0) ? 0 : (tstart - WARM);

    __shared__ __align__(16) float smB[64];   // th broadcast (1 chain)

    // ---- weights, pre-scaled; W1 pre-permuted for the DPP rotation ----
    float gswN = -L2E * gsw[i];
    float rswN = -L2E * rsw[i];
    float w1f0 = (2.f * L2E) * W1[lane * 35 + 0];
    float w1f1 = (2.f * L2E) * W1[lane * 35 + 1];
    float w1f2 = (2.f * L2E) * W1[lane * 35 + 2];
    float w1rot[32];   // step s: rot holds rv[(lane-s)&31] -> col (lane-s)&31
#pragma unroll
    for (int s = 0; s < 32; ++s)
        w1rot[s] = (2.f * L2E) * W1[lane * 35 + 3 + ((lane - s) & 31)];
    float b1l = (2.f * L2E) * b1[lane];
    float w2r[32];     // half-dot: cols (half*32)..+31 of row i
#pragma unroll
    for (int j = 0; j < 32; ++j) w2r[j] = L2E * W2[i * 64 + (half << 5) + j];
    float b2l = L2E * b2[i];

    PIN(gswN); PIN(rswN); PIN(b1l); PIN(b2l);
    PIN(w1f0); PIN(w1f1); PIN(w1f2);
#pragma unroll
    for (int s = 0; s < 32; ++s) { PIN(w1rot[s]); PIN(w2r[s]); }

    // ---- initial state (wave-uniform guess; converges during warm-up) ----
    float r00 = returns[wst];
    float v = r00 * r00;

    // ---- warm-up ----
    if (wsgl) {
        const float* gw = wsgl + (size_t)bid * WARM * SDIM;
        const float* lw = wsrl + (size_t)bid * WARM * SDIM;
        PIPE1(gw, lw, returns + wst, WARM, 0, false)
    } else {
        // cold fallback (never taken when ws present): recompute gl/rl from
        // X and global betas (L2-resident); no LDS staging.
        for (int t = 0; t < WARM; ++t) {
            const float* xr = X + (size_t)(wst + t) * 32;
            float a_ = 0.f, c_ = 0.f;
#pragma unroll
            for (int j = 0; j < 32; ++j) {
                float xe = xr[j];
                a_ = fmaf(xe, gb[j * 32 + i], a_);
                c_ = fmaf(xe, rg[j * 32 + i], c_);
            }
            a_ *= -L2E;  c_ *= -L2E;
            float rc_ = returns[wst + t];
            STEP1(0, a_, c_, rc_, false)
        }
    }

    // block 0 starts exactly (its dummy warm-up is discarded)
    if (bid == 0) {
        float r0 = returns[0];
        v = r0 * r0;
    }

    // ---- owned segment (reads clamped to own range; overwrite in place) ----
    {
        PIPE1(out_z + (size_t)tstart * SDIM, out_cand + (size_t)tstart * SDIM,
              returns + tstart, SEG, tstart, true)
    }

    // final state (mirrored; lanes 0-31 hold all 32 states)
    if (bid == NBLK - 1 && lane < SDIM) out_vfinal[i] = v;
}

// ---------------------------------------------------------------------------
extern "C" void kernel_launch(void* const* d_in, const int* in_sizes, int n_in,
                              void* d_out, int out_size, void* d_ws, size_t ws_size,
                              hipStream_t stream)
{
    const float* X          = (const float*)d_in[0];
    const float* returns    = (const float*)d_in[1];
    const float* gate_beta  = (const float*)d_in[2];
    const float* gsw        = (const float*)d_in[3];
    const float* reset_gamma= (const float*)d_in[4];
    const float* rsw        = (const float*)d_in[5];
    const float* W1         = (const float*)d_in[6];
    const float* b1         = (const float*)d_in[7];
    const float* W2         = (const float*)d_in[8];
    const float* b2         = (const float*)d_in[9];

    float* out       = (float*)d_out;
    float* out_sigma = out;                                   // [N]
    float* out_z     = out + NT;                              // [N*S]
    float* out_cand  = out + NT + (size_t)NT * SDIM;          // [N*S]
    float* out_vfin  = out + NT + 2 * (size_t)NT * SDIM;      // [S]

    const bool use_ws = (ws_size >= WS_NEEDED);
    float* wsgl = use_ws ? (float*)d_ws : nullptr;
    float* wsrl = use_ws ? ((float*)d_ws + WSW) : nullptr;

    precompute_lin<<<(NT / 2 * SDIM) / 256, 256, 0, stream>>>(
        X, gate_beta, reset_gamma, out_z, out_cand, wsgl, wsrl);

    scan_kernel<<<NBLK, 64, 0, stream>>>(
        returns, gsw, rsw, W1, b1, W2, b2,
        X, gate_beta, reset_gamma, wsgl, wsrl,
        out_sigma, out_z, out_cand, out_vfin);
}